// Round 8
// baseline (452.635 us; speedup 1.0000x reference)
//
#include <hip/hip_runtime.h>
#include <math.h>

constexpr int cN = 2, cH = 8, cL = 2048, cS = 2048, cE = 64, cD = 64;
constexpr int cC = 128, cK = 32, cB = 32, cIT = 10;
constexpr int cNH = cN * cH;          // 16
constexpr int SK = 8;                 // split-K factor for PV
constexpr int CHUNK = cS / SK;        // 256 s per split
constexpr int TILES = 8;              // point tiles per nh in k_assign
constexpr int HW = cC * 33;           // partial hist words: sbs[128][32] + scnt[128]
// TEMP = 1/sqrt(64) = 0.125 exactly

// ---------------- Kernel 1: LSH bits -------------------------------------
__global__ __launch_bounds__(256)
void k_bits(const float* __restrict__ q, const float* __restrict__ planes,
            unsigned int* __restrict__ bits)
{
    __shared__ float pl[cB * (cE + 1)];
    int tid = threadIdx.x;
    for (int i = tid; i < cB * (cE + 1); i += 256) pl[i] = planes[i];
    __syncthreads();
    int idx = blockIdx.x * 256 + tid;           // (n*H + h)*L + l
    int l = idx % cL, h = (idx / cL) % cH, n = idx / (cL * cH);
    const float* qr = q + (((size_t)n * cL + l) * cH + h) * cE;
    float qv[cE];
#pragma unroll
    for (int e4 = 0; e4 < cE / 4; ++e4) {
        float4 f = ((const float4*)qr)[e4];
        qv[4*e4+0] = f.x; qv[4*e4+1] = f.y; qv[4*e4+2] = f.z; qv[4*e4+3] = f.w;
    }
    unsigned int w = 0;
    for (int b = 0; b < cB; ++b) {
        float acc = 0.f;
#pragma unroll
        for (int e = 0; e < cE; ++e) acc = fmaf(qv[e], pl[b * (cE + 1) + e], acc);
        acc += pl[b * (cE + 1) + cE];
        if (acc > 0.f) w |= (1u << b);
    }
    bits[idx] = w;
}

// ---------------- Kernel 2a: initial centroids ---------------------------
__global__ __launch_bounds__(256)
void k_init(const unsigned int* __restrict__ bits, unsigned int* __restrict__ cent)
{
    int i = blockIdx.x * 256 + threadIdx.x;     // nh*128 + c
    int c = i & 127, nh = i >> 7;
    // idx0 = linspace(0, L-1, C).astype(int32): floor(c*2047/127), endpoint exact
    int i0 = (int)(((double)c * 2047.0) / 127.0);
    cent[i] = bits[(size_t)nh * cL + i0];
}

// ---------------- Kernel 2b: assignment + partial histograms -------------
// grid = 16 nh x 8 tiles = 128 blocks, 256 threads (1 point each)
__global__ __launch_bounds__(256)
void k_assign(const unsigned int* __restrict__ bits,
              const unsigned int* __restrict__ cent,
              int* __restrict__ partial, int* __restrict__ cl, int write_cl)
{
    __shared__ unsigned int scb[cC] __attribute__((aligned(16)));
    __shared__ int hist[HW];      // [c*32+b] bitsums, [4096+c] counts
    int tid = threadIdx.x;
    int lane = tid & 63;
    int tile = blockIdx.x & (TILES - 1), nh = blockIdx.x / TILES;
    if (tid < cC) scb[tid] = cent[nh * cC + tid];
    for (int i = tid; i < HW; i += 256) hist[i] = 0;
    int l = tile * 256 + tid;
    unsigned int w = bits[(size_t)nh * cL + l];
    // per-lane bit ballots over this wave's 64 points (lane b&31 keeps bit b)
    unsigned long long mymb = 0ull;
#pragma unroll
    for (int b = 0; b < cB; ++b) {
        unsigned long long m = __ballot((w >> b) & 1u);
        if ((lane & 31) == b) mymb = m;
    }
    __syncthreads();
    const uint4* scb4 = (const uint4*)scb;
    // packed key = (hamming<<8)|c -> min = lowest dist, tie lowest c
    int best = 0x7fffffff;
    for (int c4 = 0; c4 < cC / 4; ++c4) {
        uint4 cb = scb4[c4];
        int c = c4 * 4;
        best = min(best, (__popc(w ^ cb.x) << 8) | c);
        best = min(best, (__popc(w ^ cb.y) << 8) | (c + 1));
        best = min(best, (__popc(w ^ cb.z) << 8) | (c + 2));
        best = min(best, (__popc(w ^ cb.w) << 8) | (c + 3));
    }
    int bc = best & 255;
    if (write_cl) cl[(size_t)nh * cL + l] = bc;
    // wave-aggregated histogram into LDS (integer atomics: deterministic)
    for (int c = 0; c < cC; ++c) {
        unsigned long long m = __ballot(bc == c);
        if (m) {
            if (lane < cB) {
                int contrib = __popcll(m & mymb);
                if (contrib) atomicAdd(&hist[c * 32 + lane], contrib);
            }
            if (lane == 63) atomicAdd(&hist[4096 + c], __popcll(m));
        }
    }
    __syncthreads();
    int* dst = partial + (size_t)(nh * TILES + tile) * HW;
    for (int i = tid; i < HW; i += 256) dst[i] = hist[i];
}

// ---------------- Kernel 2c: centroid update / final counts+moff ---------
// grid = 16 blocks x 128 threads (thread = cluster)
__global__ __launch_bounds__(128)
void k_update(const int* __restrict__ partial, unsigned int* __restrict__ cent,
              int* __restrict__ counts, int* __restrict__ moff, int mode)
{
    __shared__ int scn[cC];
    int c = threadIdx.x, nh = blockIdx.x;
    int cnt = 0;
    int bs[cB];
#pragma unroll
    for (int b = 0; b < cB; ++b) bs[b] = 0;
    for (int t = 0; t < TILES; ++t) {
        const int* p = partial + (size_t)(nh * TILES + t) * HW;
        cnt += p[4096 + c];
#pragma unroll
        for (int b = 0; b < cB; ++b) bs[b] += p[c * 32 + b];
    }
    if (mode == 0) {
        if (cnt > 0) {                       // keep old centroid if empty
            unsigned int nw = 0;
#pragma unroll
            for (int b = 0; b < cB; ++b)
                if (2 * bs[b] > cnt) nw |= (1u << b);
            cent[nh * cC + c] = nw;
        }
    } else {
        counts[nh * cC + c] = cnt;
        scn[c] = cnt;
        __syncthreads();
        if (c == 0) {
            int run = 0;
            for (int i = 0; i < cC; ++i) { int v = scn[i]; scn[i] = run; run += v; }
        }
        __syncthreads();
        moff[nh * cC + c] = scn[c];          // exclusive cluster prefix
    }
}

// ---------------- Kernel 2d: parallel stable counting-sort ranks ---------
// grid = 16 nh x 8 tiles = 128 blocks, 256 threads (1 point each)
// pos = moff[nh][c] + sum_{t'<tile} partial[t'].count[c] + in-tile stable rank
__global__ __launch_bounds__(256)
void k_rank(const int* __restrict__ cl, const int* __restrict__ partial,
            const int* __restrict__ moff, int* __restrict__ mlist)
{
    __shared__ int pre[cC];
    __shared__ int wcnt[4][cC];
    int tid = threadIdx.x, lane = tid & 63, wid = tid >> 6;
    int tile = blockIdx.x & (TILES - 1), nh = blockIdx.x / TILES;
    if (tid < cC) {
        int s = 0;
        for (int t = 0; t < tile; ++t)
            s += partial[(size_t)(nh * TILES + t) * HW + 4096 + tid];
        pre[tid] = s + moff[nh * cC + tid];
    }
    int l = tile * 256 + tid;
    int bc = cl[(size_t)nh * cL + l];
    unsigned long long ltmask = (1ull << lane) - 1ull;   // lanes below me
    int myrank = 0;
    for (int c = 0; c < cC; ++c) {
        unsigned long long m = __ballot(bc == c);
        if (lane == 0) wcnt[wid][c] = __popcll(m);
        if (bc == c) myrank = __popcll(m & ltmask);
    }
    __syncthreads();
    int off = pre[bc] + myrank;
    for (int w = 0; w < 4; ++w)
        if (w < wid) off += wcnt[w][bc];
    mlist[(size_t)nh * cL + off] = l;
}

// ---------------- Kernel 3: cluster-mean queries Qg ----------------------
// one block (64 lanes = e) per (nh,c); dense member list, batched loads,
// strict ascending-l single-accumulator chain (bit-exact vs np GEMM)
__global__ __launch_bounds__(64)
void k_qg(const float* __restrict__ q, const int* __restrict__ mlist,
          const int* __restrict__ moff, const int* __restrict__ counts,
          float* __restrict__ Qg)
{
    int b = blockIdx.x;                 // nh*cC + c
    int nh = b >> 7;
    int h = nh % cH, n = nh / cH;
    int lane = threadIdx.x;
    int off = moff[b];
    int cnt = counts[b];
    const int* ml = mlist + (size_t)nh * cL + off;
    const float* qb = q + ((size_t)n * cL * cH + h) * cE + lane;
    float acc = 0.f;
    int j = 0;
    for (; j + 4 <= cnt; j += 4) {
        int i0 = ml[j], i1 = ml[j + 1], i2 = ml[j + 2], i3 = ml[j + 3];
        float v0 = qb[(size_t)i0 * cH * cE];
        float v1 = qb[(size_t)i1 * cH * cE];
        float v2 = qb[(size_t)i2 * cH * cE];
        float v3 = qb[(size_t)i3 * cH * cE];
        acc += v0; acc += v1; acc += v2; acc += v3;    // in-order chain
    }
    for (; j < cnt; ++j) acc += qb[(size_t)ml[j] * cH * cE];
    float cs = (float)(cnt > 0 ? cnt : 1);
    Qg[(size_t)b * cE + lane] = acc / cs;
}

// ---------------- Kernel 4a: QK = Qg . k^T  (tiled GEMM, exact chains) ---
// grid = nh(16) x s-tiles(16 of 128); block 256 = 16 ty (c) x 16 tx (s)
__global__ __launch_bounds__(256)
void k_qk_gemm(const float* __restrict__ key, const float* __restrict__ Qg,
               float* __restrict__ QK)
{
    __shared__ float qgT[cE][cC + 2];      // [e][c]
    __shared__ float kT[cE][128 + 2];      // [e][s_local]
    int tid = threadIdx.x;
    int bs = blockIdx.x & 15;              // s-tile
    int nh = blockIdx.x >> 4;
    int h = nh % cH, n = nh / cH;
    const float4* qsrc = (const float4*)(Qg + (size_t)nh * cC * cE);
#pragma unroll
    for (int i = 0; i < 8; ++i) {
        int f = tid + 256 * i;
        int c = f >> 4, e4 = (f & 15) << 2;
        float4 v = qsrc[f];
        qgT[e4+0][c] = v.x; qgT[e4+1][c] = v.y; qgT[e4+2][c] = v.z; qgT[e4+3][c] = v.w;
    }
    const float* kb = key + (size_t)n * cS * cH * cE + (size_t)h * cE;
    int s0 = bs * 128;
#pragma unroll
    for (int i = 0; i < 8; ++i) {
        int f = tid + 256 * i;
        int s = f >> 4, e4 = (f & 15) << 2;
        float4 v = *(const float4*)(kb + (size_t)(s0 + s) * (cH * cE) + e4);
        kT[e4+0][s] = v.x; kT[e4+1][s] = v.y; kT[e4+2][s] = v.z; kT[e4+3][s] = v.w;
    }
    __syncthreads();
    int tx = tid & 15, ty = tid >> 4;
    float acc[8][8];
#pragma unroll
    for (int i = 0; i < 8; ++i)
#pragma unroll
        for (int j = 0; j < 8; ++j) acc[i][j] = 0.f;
    for (int e = 0; e < cE; ++e) {
        float qv[8], kv[8];
#pragma unroll
        for (int i = 0; i < 8; ++i) qv[i] = qgT[e][ty + 16 * i];
#pragma unroll
        for (int j = 0; j < 8; ++j) kv[j] = kT[e][tx + 16 * j];
#pragma unroll
        for (int i = 0; i < 8; ++i)
#pragma unroll
            for (int j = 0; j < 8; ++j)
                acc[i][j] = fmaf(qv[i], kv[j], acc[i][j]);   // ascending-e chain
    }
    float* dst = QK + (size_t)nh * cC * cS + s0;
#pragma unroll
    for (int i = 0; i < 8; ++i)
#pragma unroll
        for (int j = 0; j < 8; ++j)
            dst[(size_t)(ty + 16 * i) * cS + tx + 16 * j] = acc[i][j];
}

// ---------------- Kernel 4b: per-row top-32 + softmax -> P (in-place) ----
// one block (256 threads) per (n,h,c) row
__global__ __launch_bounds__(256)
void k_sel(float* __restrict__ QK, int* __restrict__ topk,
           float* __restrict__ abk)
{
    __shared__ float row[cS];
    __shared__ float work[cS];
    __shared__ float rv[4];
    __shared__ int   ri[4];
    __shared__ int   stopk[cK];
    __shared__ float sM, sDen;
    int tid = threadIdx.x;
    int lane = tid & 63, wid = tid >> 6;
    int b = blockIdx.x;                 // (n*H + h)*C + c
    float* qrow = QK + (size_t)b * cS;
    for (int j = 0; j < cS / 256; ++j) {
        int s = tid + j * 256;
        float v = qrow[s];
        row[s] = v; work[s] = v;
    }
    __syncthreads();
    // iterative top-32, tie -> lower index (jax.lax.top_k semantics)
    for (int itk = 0; itk < cK; ++itk) {
        float bv = -INFINITY; int bi = 0x7fffffff;
        for (int j = 0; j < cS / 256; ++j) {
            int s = tid + j * 256;
            float v = work[s];
            if (v > bv) { bv = v; bi = s; }
        }
#pragma unroll
        for (int off = 32; off; off >>= 1) {
            float ov = __shfl_xor(bv, off);
            int   oi = __shfl_xor(bi, off);
            if (ov > bv || (ov == bv && oi < bi)) { bv = ov; bi = oi; }
        }
        if (lane == 0) { rv[wid] = bv; ri[wid] = bi; }
        __syncthreads();
        if (tid == 0) {
            float v = rv[0]; int i = ri[0];
            for (int wv = 1; wv < 4; ++wv)
                if (rv[wv] > v || (rv[wv] == v && ri[wv] < i)) { v = rv[wv]; i = ri[wv]; }
            stopk[itk] = i;
            work[i] = -INFINITY;
        }
        __syncthreads();
    }
    if (tid < cK) topk[(size_t)b * cK + tid] = stopk[tid];
    // softmax over full row (TEMP=0.125 scaling exact; shift by max)
    float mv = -INFINITY;
    for (int j = 0; j < cS / 256; ++j) mv = fmaxf(mv, row[tid + j * 256]);
#pragma unroll
    for (int off = 32; off; off >>= 1) mv = fmaxf(mv, __shfl_xor(mv, off));
    if (lane == 0) rv[wid] = mv;
    __syncthreads();
    if (tid == 0) sM = fmaxf(fmaxf(rv[0], rv[1]), fmaxf(rv[2], rv[3]));
    __syncthreads();
    float M = sM;
    float psum = 0.f;
    for (int j = 0; j < cS / 256; ++j) {
        int s = tid + j * 256;
        float e = expf(0.125f * (row[s] - M));
        work[s] = e;
        psum += e;
    }
#pragma unroll
    for (int off = 32; off; off >>= 1) psum += __shfl_xor(psum, off);
    if (lane == 0) rv[wid] = psum;
    __syncthreads();
    if (tid == 0) sDen = ((rv[0] + rv[1]) + rv[2]) + rv[3];
    __syncthreads();
    float den = sDen;
    for (int j = 0; j < cS / 256; ++j) { int s = tid + j * 256; work[s] = work[s] / den; }
    __syncthreads();
    if (tid < cK) work[stopk[tid]] = 0.f;        // mask out top-k
    __syncthreads();
    // A_bottomk
    float ps = 0.f;
    for (int j = 0; j < cS / 256; ++j) ps += work[tid + j * 256];
#pragma unroll
    for (int off = 32; off; off >>= 1) ps += __shfl_xor(ps, off);
    if (lane == 0) rv[wid] = ps;
    __syncthreads();
    if (tid == 0) abk[b] = ((rv[0] + rv[1]) + rv[2]) + rv[3];
    // write P back in place (normalized, top-k zeroed)
    for (int j = 0; j < cS / 256; ++j) { int s = tid + j * 256; qrow[s] = work[s]; }
}

// ---------------- Kernel 4c: Vb_g partials = P . v (split-K GEMM) --------
// grid = nh(16) x sk(8) x ch(2);  block 256 = 16 ty (c) x 16 tx (d4)
__global__ __launch_bounds__(256)
void k_pv(const float* __restrict__ P, const float* __restrict__ val,
          float* __restrict__ part)
{
    __shared__ float pT[64][64 + 2];       // [c_local][s_sub]
    __shared__ float vT[64][cD + 4];       // [s_sub][d]
    int tid = threadIdx.x;
    int ch = blockIdx.x & 1;
    int sk = (blockIdx.x >> 1) & 7;
    int nh = blockIdx.x >> 4;
    int h = nh % cH, n = nh / cH;
    int tx = tid & 15, ty = tid >> 4;
    float acc[4][4];
#pragma unroll
    for (int i = 0; i < 4; ++i)
#pragma unroll
        for (int j = 0; j < 4; ++j) acc[i][j] = 0.f;
    const float* pb = P + ((size_t)nh * cC + ch * 64) * cS;
    const float* vb = val + (size_t)n * cS * cH * cD + (size_t)h * cD;
    for (int sub = 0; sub < CHUNK / 64; ++sub) {
        int s0 = sk * CHUNK + sub * 64;
#pragma unroll
        for (int i = 0; i < 4; ++i) {
            int f = tid + 256 * i;
            int c = f >> 4, s4 = (f & 15) << 2;
            float4 v = *(const float4*)(pb + (size_t)c * cS + s0 + s4);
            pT[c][s4+0] = v.x; pT[c][s4+1] = v.y; pT[c][s4+2] = v.z; pT[c][s4+3] = v.w;
        }
#pragma unroll
        for (int i = 0; i < 4; ++i) {
            int f = tid + 256 * i;
            int ss = f >> 4, d4 = (f & 15) << 2;
            float4 v = *(const float4*)(vb + (size_t)(s0 + ss) * (cH * cD) + d4);
            vT[ss][d4+0] = v.x; vT[ss][d4+1] = v.y; vT[ss][d4+2] = v.z; vT[ss][d4+3] = v.w;
        }
        __syncthreads();
        for (int ss = 0; ss < 64; ++ss) {
            float pv[4];
#pragma unroll
            for (int i = 0; i < 4; ++i) pv[i] = pT[ty + 16 * i][ss];
            float4 vv = *(const float4*)&vT[ss][tx * 4];
#pragma unroll
            for (int i = 0; i < 4; ++i) {
                acc[i][0] = fmaf(pv[i], vv.x, acc[i][0]);
                acc[i][1] = fmaf(pv[i], vv.y, acc[i][1]);
                acc[i][2] = fmaf(pv[i], vv.z, acc[i][2]);
                acc[i][3] = fmaf(pv[i], vv.w, acc[i][3]);
            }
        }
        __syncthreads();
    }
    float* dst = part + (((size_t)sk * cNH + nh) * cC + ch * 64) * cD;
#pragma unroll
    for (int i = 0; i < 4; ++i) {
        float4 o; o.x = acc[i][0]; o.y = acc[i][1]; o.z = acc[i][2]; o.w = acc[i][3];
        *(float4*)(dst + (size_t)(ty + 16 * i) * cD + tx * 4) = o;
    }
}

// ---------------- Kernel 4d: reduce split-K partials ---------------------
__global__ __launch_bounds__(256)
void k_red(const float* __restrict__ part, float* __restrict__ vbg)
{
    int i = blockIdx.x * 256 + threadIdx.x;      // over 16*128*64 = 131072
    float acc = 0.f;
    for (int sk = 0; sk < SK; ++sk) acc += part[(size_t)sk * (cNH * cC * cD) + i];
    vbg[i] = acc;
}

// ---------------- Kernel 5: per-cluster epilogue -------------------------
// one block per (nh,c); K_sel/V_sel staged once; 4 waves iterate members.
// All FP chains keep the validated operand order -> bit-identical outputs.
__global__ __launch_bounds__(256)
void k_out(const float* __restrict__ q, const float* __restrict__ key,
           const float* __restrict__ val, const int* __restrict__ mlist,
           const int* __restrict__ moff, const int* __restrict__ counts,
           const float* __restrict__ abk, const float* __restrict__ vbg,
           const int* __restrict__ topk, float* __restrict__ out)
{
    __shared__ float klds[cK][cE + 2];
    __shared__ float vlds[cK][cD + 2];
    __shared__ int   st[cK];
    int tid = threadIdx.x, lane = tid & 63, wid = tid >> 6;
    int b = blockIdx.x;                 // nh*cC + c
    int nh = b >> 7;
    int h = nh % cH, n = nh / cH;
    if (tid < cK) st[tid] = topk[(size_t)b * cK + tid];
    __syncthreads();
    const float* kb = key + ((size_t)n * cS * cH + h) * cE;
    const float* vb = val + ((size_t)n * cS * cH + h) * cD;
    for (int r = tid >> 6; r < cK; r += 4) {
        int t = st[r];
        klds[r][lane] = kb[(size_t)t * cH * cE + lane];
        vlds[r][lane] = vb[(size_t)t * cH * cD + lane];
    }
    __syncthreads();
    int cnt = counts[b];
    int off = moff[b];
    float scale = 1.0f - abk[b];
    float vbgd = vbg[(size_t)b * cD + lane];
    float stf = (lane < cK) ? (float)st[lane] : 0.f;
    const int* ml = mlist + (size_t)nh * cL + off;
    const size_t off1 = (size_t)cN * cL * cH * cD;
    const size_t off2 = off1 + (size_t)cN * cH * cL * cK;
    int kr = lane & 31;                 // lanes 32..63 duplicate 0..31 (no divergence)
    for (int m = wid; m < cnt; m += 4) {
        int l = ml[m];
        float qv = q[(((size_t)n * cL + l) * cH + h) * cE + lane];
        // QK: ascending-e fmaf chain, q broadcast via readlane
        float qk = 0.f;
#pragma unroll
        for (int e = 0; e < cE; ++e)
            qk = fmaf(__shfl(qv, e), klds[kr][e], qk);
        // max over the 32 scores: shuffle-tree fmax (bitwise == serial chain)
        float M = qk;
#pragma unroll
        for (int o = 16; o; o >>= 1) M = fmaxf(M, __shfl_xor(M, o, 32));
        float ev = expf(0.125f * (qk - M));
        // den: ascending-j sum of the same 32 exp values (identical chain)
        float den = 0.f;
#pragma unroll
        for (int j = 0; j < cK; ++j) den += __shfl(ev, j);
        float as_ = (ev / den) * scale;                  // A_s (lane<32 valid)
        // PV: ascending-j fmaf chain, A_s broadcast via readlane
        float acc = 0.f;
#pragma unroll
        for (int j = 0; j < cK; ++j)
            acc = fmaf(__shfl(as_, j), vlds[j][lane], acc);
        acc += vbgd;
        int qidx = nh * cL + l;
        out[(((size_t)n * cL + l) * cH + h) * cD + lane] = acc;   // (N,L,H,D)
        if (lane < cK) {
            out[off1 + (size_t)qidx * cK + lane] = stf;           // sparse_index
            out[off2 + (size_t)qidx * cK + lane] = as_;           // A_topk
        }
    }
}

// ---------------- launch -------------------------------------------------
extern "C" void kernel_launch(void* const* d_in, const int* in_sizes, int n_in,
                              void* d_out, int out_size, void* d_ws, size_t ws_size,
                              hipStream_t stream)
{
    (void)in_sizes; (void)n_in; (void)out_size; (void)ws_size;
    const float* q      = (const float*)d_in[0];
    const float* key    = (const float*)d_in[1];
    const float* val    = (const float*)d_in[2];
    const float* planes = (const float*)d_in[3];
    char* w = (char*)d_ws;
    unsigned int* bits = (unsigned int*)w;  w += (size_t)cN * cH * cL * 4;
    int*   cl     = (int*)w;                w += (size_t)cN * cH * cL * 4;
    int*   counts = (int*)w;                w += (size_t)cN * cH * cC * 4;
    float* abk    = (float*)w;              w += (size_t)cN * cH * cC * 4;
    float* Qg     = (float*)w;              w += (size_t)cN * cH * cC * cE * 4;
    float* vbg    = (float*)w;              w += (size_t)cN * cH * cC * cD * 4;
    int*   topkp  = (int*)w;                w += (size_t)cN * cH * cC * cK * 4;
    float* QK     = (float*)w;              w += (size_t)cNH * cC * cS * 4;      // 16 MB (QK -> P in place)
    float* part   = (float*)w;              w += (size_t)SK * cNH * cC * cD * 4; // 4 MB
    unsigned int* cent = (unsigned int*)w;  w += (size_t)cNH * cC * 4;           // 8 KB
    int*   partial = (int*)w;               w += (size_t)cNH * TILES * HW * 4;   // 2.2 MB
    int*   mlist  = (int*)w;                w += (size_t)cNH * cL * 4;           // 128 KB
    int*   moff   = (int*)w;                w += (size_t)cNH * cC * 4;           // 8 KB
    float* out = (float*)d_out;

    k_bits   <<<(cN * cH * cL) / 256, 256, 0, stream>>>(q, planes, bits);
    k_init   <<<(cNH * cC) / 256, 256, 0, stream>>>(bits, cent);
    for (int it = 0; it < cIT; ++it) {
        k_assign <<<cNH * TILES, 256, 0, stream>>>(bits, cent, partial, cl, 0);
        k_update <<<cNH, 128, 0, stream>>>(partial, cent, counts, moff, 0);
    }
    k_assign <<<cNH * TILES, 256, 0, stream>>>(bits, cent, partial, cl, 1);
    k_update <<<cNH, 128, 0, stream>>>(partial, cent, counts, moff, 1);
    k_rank   <<<cNH * TILES, 256, 0, stream>>>(cl, partial, moff, mlist);
    k_qg     <<<cNH * cC, 64, 0, stream>>>(q, mlist, moff, counts, Qg);
    k_qk_gemm<<<cNH * 16, 256, 0, stream>>>(key, Qg, QK);
    k_sel    <<<cNH * cC, 256, 0, stream>>>(QK, topkp, abk);
    k_pv     <<<cNH * SK * 2, 256, 0, stream>>>(QK, val, part);
    k_red    <<<(cNH * cC * cD) / 256, 256, 0, stream>>>(part, vbg);
    k_out    <<<cNH * cC, 256, 0, stream>>>(q, key, val, mlist, moff, counts,
                                            abk, vbg, topkp, out);
}

// Round 9
// 417.074 us; speedup vs baseline: 1.0853x; 1.0853x over previous
//
#include <hip/hip_runtime.h>
#include <math.h>

constexpr int cN = 2, cH = 8, cL = 2048, cS = 2048, cE = 64, cD = 64;
constexpr int cC = 128, cK = 32, cB = 32, cIT = 10;
constexpr int cNH = cN * cH;          // 16
constexpr int SK = 8;                 // split-K factor for PV
constexpr int CHUNK = cS / SK;        // 256 s per split
constexpr int TILES = 8;              // point tiles per nh in k_assign
constexpr int HW = cC * 33;           // partial hist words: sbs[128][32] + scnt[128]
constexpr int OSPLIT = 2;             // blocks per cluster in k_out
// TEMP = 1/sqrt(64) = 0.125 exactly

// ---------------- Kernel 1: LSH bits -------------------------------------
__global__ __launch_bounds__(256)
void k_bits(const float* __restrict__ q, const float* __restrict__ planes,
            unsigned int* __restrict__ bits)
{
    __shared__ float pl[cB * (cE + 1)];
    int tid = threadIdx.x;
    for (int i = tid; i < cB * (cE + 1); i += 256) pl[i] = planes[i];
    __syncthreads();
    int idx = blockIdx.x * 256 + tid;           // (n*H + h)*L + l
    int l = idx % cL, h = (idx / cL) % cH, n = idx / (cL * cH);
    const float* qr = q + (((size_t)n * cL + l) * cH + h) * cE;
    float qv[cE];
#pragma unroll
    for (int e4 = 0; e4 < cE / 4; ++e4) {
        float4 f = ((const float4*)qr)[e4];
        qv[4*e4+0] = f.x; qv[4*e4+1] = f.y; qv[4*e4+2] = f.z; qv[4*e4+3] = f.w;
    }
    unsigned int w = 0;
    for (int b = 0; b < cB; ++b) {
        float acc = 0.f;
#pragma unroll
        for (int e = 0; e < cE; ++e) acc = fmaf(qv[e], pl[b * (cE + 1) + e], acc);
        acc += pl[b * (cE + 1) + cE];
        if (acc > 0.f) w |= (1u << b);
    }
    bits[idx] = w;
}

// ---------------- Kernel 2a: initial centroids ---------------------------
__global__ __launch_bounds__(256)
void k_init(const unsigned int* __restrict__ bits, unsigned int* __restrict__ cent)
{
    int i = blockIdx.x * 256 + threadIdx.x;     // nh*128 + c
    int c = i & 127, nh = i >> 7;
    // idx0 = linspace(0, L-1, C).astype(int32): floor(c*2047/127), endpoint exact
    int i0 = (int)(((double)c * 2047.0) / 127.0);
    cent[i] = bits[(size_t)nh * cL + i0];
}

// ---------------- Kernel 2b: assignment + partial histograms -------------
// grid = 16 nh x 8 tiles = 128 blocks, 256 threads (1 point each)
__global__ __launch_bounds__(256)
void k_assign(const unsigned int* __restrict__ bits,
              const unsigned int* __restrict__ cent,
              int* __restrict__ partial, int* __restrict__ cl, int write_cl)
{
    __shared__ unsigned int scb[cC] __attribute__((aligned(16)));
    __shared__ int hist[HW];      // [c*32+b] bitsums, [4096+c] counts
    int tid = threadIdx.x;
    int lane = tid & 63;
    int tile = blockIdx.x & (TILES - 1), nh = blockIdx.x / TILES;
    if (tid < cC) scb[tid] = cent[nh * cC + tid];
    for (int i = tid; i < HW; i += 256) hist[i] = 0;
    int l = tile * 256 + tid;
    unsigned int w = bits[(size_t)nh * cL + l];
    // per-lane bit ballots over this wave's 64 points (lane b&31 keeps bit b)
    unsigned long long mymb = 0ull;
#pragma unroll
    for (int b = 0; b < cB; ++b) {
        unsigned long long m = __ballot((w >> b) & 1u);
        if ((lane & 31) == b) mymb = m;
    }
    __syncthreads();
    const uint4* scb4 = (const uint4*)scb;
    // packed key = (hamming<<8)|c -> min = lowest dist, tie lowest c
    int best = 0x7fffffff;
    for (int c4 = 0; c4 < cC / 4; ++c4) {
        uint4 cb = scb4[c4];
        int c = c4 * 4;
        best = min(best, (__popc(w ^ cb.x) << 8) | c);
        best = min(best, (__popc(w ^ cb.y) << 8) | (c + 1));
        best = min(best, (__popc(w ^ cb.z) << 8) | (c + 2));
        best = min(best, (__popc(w ^ cb.w) << 8) | (c + 3));
    }
    int bc = best & 255;
    if (write_cl) cl[(size_t)nh * cL + l] = bc;
    // wave-aggregated histogram into LDS (integer atomics: deterministic)
    for (int c = 0; c < cC; ++c) {
        unsigned long long m = __ballot(bc == c);
        if (m) {
            if (lane < cB) {
                int contrib = __popcll(m & mymb);
                if (contrib) atomicAdd(&hist[c * 32 + lane], contrib);
            }
            if (lane == 63) atomicAdd(&hist[4096 + c], __popcll(m));
        }
    }
    __syncthreads();
    int* dst = partial + (size_t)(nh * TILES + tile) * HW;
    for (int i = tid; i < HW; i += 256) dst[i] = hist[i];
}

// ---------------- Kernel 2c: centroid update / final counts+moff ---------
// grid = 16 blocks x 128 threads (thread = cluster)
__global__ __launch_bounds__(128)
void k_update(const int* __restrict__ partial, unsigned int* __restrict__ cent,
              int* __restrict__ counts, int* __restrict__ moff, int mode)
{
    __shared__ int scn[cC];
    int c = threadIdx.x, nh = blockIdx.x;
    int cnt = 0;
    int bs[cB];
#pragma unroll
    for (int b = 0; b < cB; ++b) bs[b] = 0;
    for (int t = 0; t < TILES; ++t) {
        const int* p = partial + (size_t)(nh * TILES + t) * HW;
        cnt += p[4096 + c];
#pragma unroll
        for (int b = 0; b < cB; ++b) bs[b] += p[c * 32 + b];
    }
    if (mode == 0) {
        if (cnt > 0) {                       // keep old centroid if empty
            unsigned int nw = 0;
#pragma unroll
            for (int b = 0; b < cB; ++b)
                if (2 * bs[b] > cnt) nw |= (1u << b);
            cent[nh * cC + c] = nw;
        }
    } else {
        counts[nh * cC + c] = cnt;
        scn[c] = cnt;
        __syncthreads();
        if (c == 0) {
            int run = 0;
            for (int i = 0; i < cC; ++i) { int v = scn[i]; scn[i] = run; run += v; }
        }
        __syncthreads();
        moff[nh * cC + c] = scn[c];          // exclusive cluster prefix
    }
}

// ---------------- Kernel 2d: parallel stable counting-sort ranks ---------
// grid = 16 nh x 8 tiles = 128 blocks, 256 threads (1 point each)
// pos = moff[nh][c] + sum_{t'<tile} partial[t'].count[c] + in-tile stable rank
__global__ __launch_bounds__(256)
void k_rank(const int* __restrict__ cl, const int* __restrict__ partial,
            const int* __restrict__ moff, int* __restrict__ mlist)
{
    __shared__ int pre[cC];
    __shared__ int wcnt[4][cC];
    int tid = threadIdx.x, lane = tid & 63, wid = tid >> 6;
    int tile = blockIdx.x & (TILES - 1), nh = blockIdx.x / TILES;
    if (tid < cC) {
        int s = 0;
        for (int t = 0; t < tile; ++t)
            s += partial[(size_t)(nh * TILES + t) * HW + 4096 + tid];
        pre[tid] = s + moff[nh * cC + tid];
    }
    int l = tile * 256 + tid;
    int bc = cl[(size_t)nh * cL + l];
    unsigned long long ltmask = (1ull << lane) - 1ull;   // lanes below me
    int myrank = 0;
    for (int c = 0; c < cC; ++c) {
        unsigned long long m = __ballot(bc == c);
        if (lane == 0) wcnt[wid][c] = __popcll(m);
        if (bc == c) myrank = __popcll(m & ltmask);
    }
    __syncthreads();
    int off = pre[bc] + myrank;
    for (int w = 0; w < 4; ++w)
        if (w < wid) off += wcnt[w][bc];
    mlist[(size_t)nh * cL + off] = l;
}

// ---------------- Kernel 3: cluster-mean queries Qg ----------------------
// one block (64 lanes = e) per (nh,c); dense member list, batched loads,
// strict ascending-l single-accumulator chain (bit-exact vs np GEMM)
__global__ __launch_bounds__(64)
void k_qg(const float* __restrict__ q, const int* __restrict__ mlist,
          const int* __restrict__ moff, const int* __restrict__ counts,
          float* __restrict__ Qg)
{
    int b = blockIdx.x;                 // nh*cC + c
    int nh = b >> 7;
    int h = nh % cH, n = nh / cH;
    int lane = threadIdx.x;
    int off = moff[b];
    int cnt = counts[b];
    const int* ml = mlist + (size_t)nh * cL + off;
    const float* qb = q + ((size_t)n * cL * cH + h) * cE + lane;
    float acc = 0.f;
    int j = 0;
    for (; j + 4 <= cnt; j += 4) {
        int i0 = ml[j], i1 = ml[j + 1], i2 = ml[j + 2], i3 = ml[j + 3];
        float v0 = qb[(size_t)i0 * cH * cE];
        float v1 = qb[(size_t)i1 * cH * cE];
        float v2 = qb[(size_t)i2 * cH * cE];
        float v3 = qb[(size_t)i3 * cH * cE];
        acc += v0; acc += v1; acc += v2; acc += v3;    // in-order chain
    }
    for (; j < cnt; ++j) acc += qb[(size_t)ml[j] * cH * cE];
    float cs = (float)(cnt > 0 ? cnt : 1);
    Qg[(size_t)b * cE + lane] = acc / cs;
}

// ---------------- Kernel 4a: QK = Qg . k^T  (tiled GEMM, exact chains) ---
// grid = nh(16) x s-tiles(16 of 128); block 256 = 16 ty (c) x 16 tx (s)
__global__ __launch_bounds__(256)
void k_qk_gemm(const float* __restrict__ key, const float* __restrict__ Qg,
               float* __restrict__ QK)
{
    __shared__ float qgT[cE][cC + 2];      // [e][c]
    __shared__ float kT[cE][128 + 2];      // [e][s_local]
    int tid = threadIdx.x;
    int bs = blockIdx.x & 15;              // s-tile
    int nh = blockIdx.x >> 4;
    int h = nh % cH, n = nh / cH;
    const float4* qsrc = (const float4*)(Qg + (size_t)nh * cC * cE);
#pragma unroll
    for (int i = 0; i < 8; ++i) {
        int f = tid + 256 * i;
        int c = f >> 4, e4 = (f & 15) << 2;
        float4 v = qsrc[f];
        qgT[e4+0][c] = v.x; qgT[e4+1][c] = v.y; qgT[e4+2][c] = v.z; qgT[e4+3][c] = v.w;
    }
    const float* kb = key + (size_t)n * cS * cH * cE + (size_t)h * cE;
    int s0 = bs * 128;
#pragma unroll
    for (int i = 0; i < 8; ++i) {
        int f = tid + 256 * i;
        int s = f >> 4, e4 = (f & 15) << 2;
        float4 v = *(const float4*)(kb + (size_t)(s0 + s) * (cH * cE) + e4);
        kT[e4+0][s] = v.x; kT[e4+1][s] = v.y; kT[e4+2][s] = v.z; kT[e4+3][s] = v.w;
    }
    __syncthreads();
    int tx = tid & 15, ty = tid >> 4;
    float acc[8][8];
#pragma unroll
    for (int i = 0; i < 8; ++i)
#pragma unroll
        for (int j = 0; j < 8; ++j) acc[i][j] = 0.f;
    for (int e = 0; e < cE; ++e) {
        float qv[8], kv[8];
#pragma unroll
        for (int i = 0; i < 8; ++i) qv[i] = qgT[e][ty + 16 * i];
#pragma unroll
        for (int j = 0; j < 8; ++j) kv[j] = kT[e][tx + 16 * j];
#pragma unroll
        for (int i = 0; i < 8; ++i)
#pragma unroll
            for (int j = 0; j < 8; ++j)
                acc[i][j] = fmaf(qv[i], kv[j], acc[i][j]);   // ascending-e chain
    }
    float* dst = QK + (size_t)nh * cC * cS + s0;
#pragma unroll
    for (int i = 0; i < 8; ++i)
#pragma unroll
        for (int j = 0; j < 8; ++j)
            dst[(size_t)(ty + 16 * i) * cS + tx + 16 * j] = acc[i][j];
}

// ---------------- Kernel 4b: per-row top-32 + softmax -> P (in-place) ----
// one block (256 threads) per (n,h,c) row
__global__ __launch_bounds__(256)
void k_sel(float* __restrict__ QK, int* __restrict__ topk,
           float* __restrict__ abk)
{
    __shared__ float row[cS];
    __shared__ float work[cS];
    __shared__ float rv[4];
    __shared__ int   ri[4];
    __shared__ int   stopk[cK];
    __shared__ float sM, sDen;
    int tid = threadIdx.x;
    int lane = tid & 63, wid = tid >> 6;
    int b = blockIdx.x;                 // (n*H + h)*C + c
    float* qrow = QK + (size_t)b * cS;
    for (int j = 0; j < cS / 256; ++j) {
        int s = tid + j * 256;
        float v = qrow[s];
        row[s] = v; work[s] = v;
    }
    __syncthreads();
    // iterative top-32, tie -> lower index (jax.lax.top_k semantics)
    for (int itk = 0; itk < cK; ++itk) {
        float bv = -INFINITY; int bi = 0x7fffffff;
        for (int j = 0; j < cS / 256; ++j) {
            int s = tid + j * 256;
            float v = work[s];
            if (v > bv) { bv = v; bi = s; }
        }
#pragma unroll
        for (int off = 32; off; off >>= 1) {
            float ov = __shfl_xor(bv, off);
            int   oi = __shfl_xor(bi, off);
            if (ov > bv || (ov == bv && oi < bi)) { bv = ov; bi = oi; }
        }
        if (lane == 0) { rv[wid] = bv; ri[wid] = bi; }
        __syncthreads();
        if (tid == 0) {
            float v = rv[0]; int i = ri[0];
            for (int wv = 1; wv < 4; ++wv)
                if (rv[wv] > v || (rv[wv] == v && ri[wv] < i)) { v = rv[wv]; i = ri[wv]; }
            stopk[itk] = i;
            work[i] = -INFINITY;
        }
        __syncthreads();
    }
    if (tid < cK) topk[(size_t)b * cK + tid] = stopk[tid];
    // softmax over full row (TEMP=0.125 scaling exact; shift by max)
    float mv = -INFINITY;
    for (int j = 0; j < cS / 256; ++j) mv = fmaxf(mv, row[tid + j * 256]);
#pragma unroll
    for (int off = 32; off; off >>= 1) mv = fmaxf(mv, __shfl_xor(mv, off));
    if (lane == 0) rv[wid] = mv;
    __syncthreads();
    if (tid == 0) sM = fmaxf(fmaxf(rv[0], rv[1]), fmaxf(rv[2], rv[3]));
    __syncthreads();
    float M = sM;
    float psum = 0.f;
    for (int j = 0; j < cS / 256; ++j) {
        int s = tid + j * 256;
        float e = expf(0.125f * (row[s] - M));
        work[s] = e;
        psum += e;
    }
#pragma unroll
    for (int off = 32; off; off >>= 1) psum += __shfl_xor(psum, off);
    if (lane == 0) rv[wid] = psum;
    __syncthreads();
    if (tid == 0) sDen = ((rv[0] + rv[1]) + rv[2]) + rv[3];
    __syncthreads();
    float den = sDen;
    for (int j = 0; j < cS / 256; ++j) { int s = tid + j * 256; work[s] = work[s] / den; }
    __syncthreads();
    if (tid < cK) work[stopk[tid]] = 0.f;        // mask out top-k
    __syncthreads();
    // A_bottomk
    float ps = 0.f;
    for (int j = 0; j < cS / 256; ++j) ps += work[tid + j * 256];
#pragma unroll
    for (int off = 32; off; off >>= 1) ps += __shfl_xor(ps, off);
    if (lane == 0) rv[wid] = ps;
    __syncthreads();
    if (tid == 0) abk[b] = ((rv[0] + rv[1]) + rv[2]) + rv[3];
    // write P back in place (normalized, top-k zeroed)
    for (int j = 0; j < cS / 256; ++j) { int s = tid + j * 256; qrow[s] = work[s]; }
}

// ---------------- Kernel 4c: Vb_g partials = P . v (split-K GEMM) --------
// grid = nh(16) x sk(8) x ch(2);  block 256 = 16 ty (c) x 16 tx (d4)
__global__ __launch_bounds__(256)
void k_pv(const float* __restrict__ P, const float* __restrict__ val,
          float* __restrict__ part)
{
    __shared__ float pT[64][64 + 2];       // [c_local][s_sub]
    __shared__ float vT[64][cD + 4];       // [s_sub][d]
    int tid = threadIdx.x;
    int ch = blockIdx.x & 1;
    int sk = (blockIdx.x >> 1) & 7;
    int nh = blockIdx.x >> 4;
    int h = nh % cH, n = nh / cH;
    int tx = tid & 15, ty = tid >> 4;
    float acc[4][4];
#pragma unroll
    for (int i = 0; i < 4; ++i)
#pragma unroll
        for (int j = 0; j < 4; ++j) acc[i][j] = 0.f;
    const float* pb = P + ((size_t)nh * cC + ch * 64) * cS;
    const float* vb = val + (size_t)n * cS * cH * cD + (size_t)h * cD;
    for (int sub = 0; sub < CHUNK / 64; ++sub) {
        int s0 = sk * CHUNK + sub * 64;
#pragma unroll
        for (int i = 0; i < 4; ++i) {
            int f = tid + 256 * i;
            int c = f >> 4, s4 = (f & 15) << 2;
            float4 v = *(const float4*)(pb + (size_t)c * cS + s0 + s4);
            pT[c][s4+0] = v.x; pT[c][s4+1] = v.y; pT[c][s4+2] = v.z; pT[c][s4+3] = v.w;
        }
#pragma unroll
        for (int i = 0; i < 4; ++i) {
            int f = tid + 256 * i;
            int ss = f >> 4, d4 = (f & 15) << 2;
            float4 v = *(const float4*)(vb + (size_t)(s0 + ss) * (cH * cD) + d4);
            vT[ss][d4+0] = v.x; vT[ss][d4+1] = v.y; vT[ss][d4+2] = v.z; vT[ss][d4+3] = v.w;
        }
        __syncthreads();
        for (int ss = 0; ss < 64; ++ss) {
            float pv[4];
#pragma unroll
            for (int i = 0; i < 4; ++i) pv[i] = pT[ty + 16 * i][ss];
            float4 vv = *(const float4*)&vT[ss][tx * 4];
#pragma unroll
            for (int i = 0; i < 4; ++i) {
                acc[i][0] = fmaf(pv[i], vv.x, acc[i][0]);
                acc[i][1] = fmaf(pv[i], vv.y, acc[i][1]);
                acc[i][2] = fmaf(pv[i], vv.z, acc[i][2]);
                acc[i][3] = fmaf(pv[i], vv.w, acc[i][3]);
            }
        }
        __syncthreads();
    }
    float* dst = part + (((size_t)sk * cNH + nh) * cC + ch * 64) * cD;
#pragma unroll
    for (int i = 0; i < 4; ++i) {
        float4 o; o.x = acc[i][0]; o.y = acc[i][1]; o.z = acc[i][2]; o.w = acc[i][3];
        *(float4*)(dst + (size_t)(ty + 16 * i) * cD + tx * 4) = o;
    }
}

// ---------------- Kernel 4d: reduce split-K partials ---------------------
__global__ __launch_bounds__(256)
void k_red(const float* __restrict__ part, float* __restrict__ vbg)
{
    int i = blockIdx.x * 256 + threadIdx.x;      // over 16*128*64 = 131072
    float acc = 0.f;
    for (int sk = 0; sk < SK; ++sk) acc += part[(size_t)sk * (cNH * cC * cD) + i];
    vbg[i] = acc;
}

// ---------------- Kernel 5: per-cluster epilogue (lane-parallel) ---------
// grid = cluster x OSPLIT; K^T/V staged in LDS once; per member:
// lane=(k,half) computes half-dot (q in registers), 1 shfl_xor combine,
// xor-tree max/den (tolerance-safe: feeds float outputs only), A_s via
// per-wave LDS slot, PV = 32 broadcast-read fmafs. No serial shfl chains.
__global__ __launch_bounds__(256)
void k_out(const float* __restrict__ q, const float* __restrict__ key,
           const float* __restrict__ val, const int* __restrict__ mlist,
           const int* __restrict__ moff, const int* __restrict__ counts,
           const float* __restrict__ abk, const float* __restrict__ vbg,
           const int* __restrict__ topk, float* __restrict__ out)
{
    __shared__ float klds[cE][cK + 1];   // [e][k]: store/load 2-way alias (free)
    __shared__ float vlds[cK][cD + 1];   // [k][d]: 2-way alias (free)
    __shared__ float aslds[4][cK];
    __shared__ int   st[cK];
    int tid = threadIdx.x, lane = tid & 63, wid = tid >> 6;
    int bb = blockIdx.x;
    int p = bb & (OSPLIT - 1);
    int b = bb / OSPLIT;                // nh*cC + c
    int nh = b >> 7;
    int h = nh % cH, n = nh / cH;
    if (tid < cK) st[tid] = topk[(size_t)b * cK + tid];
    __syncthreads();
    const float* kb = key + ((size_t)n * cS * cH + h) * cE;
    const float* vb = val + ((size_t)n * cS * cH + h) * cD;
    for (int r = wid; r < cK; r += 4) {
        int t = st[r];
        klds[lane][r] = kb[(size_t)t * cH * cE + lane];   // transposed
        vlds[r][lane] = vb[(size_t)t * cH * cD + lane];
    }
    __syncthreads();
    int cnt = counts[b];
    int off = moff[b];
    float scale = 1.0f - abk[b];
    float vbgd = vbg[(size_t)b * cD + lane];
    float stf = (lane < cK) ? (float)st[lane] : 0.f;
    const int* ml = mlist + (size_t)nh * cL + off;
    const size_t off1 = (size_t)cN * cL * cH * cD;
    const size_t off2 = off1 + (size_t)cN * cH * cL * cK;
    int k = lane >> 1, hh = lane & 1;
    for (int m = p * 4 + wid; m < cnt; m += 4 * OSPLIT) {   // wave-uniform loop
        int l = ml[m];
        const float* qrow = q + (((size_t)n * cL + l) * cH + h) * cE + hh * 32;
        float4 qf[8];
#pragma unroll
        for (int j = 0; j < 8; ++j) qf[j] = ((const float4*)qrow)[j];
        // half-dot: ascending e within my half
        float partial = 0.f;
#pragma unroll
        for (int j = 0; j < 8; ++j) {
            int e = hh * 32 + 4 * j;
            partial = fmaf(qf[j].x, klds[e + 0][k], partial);
            partial = fmaf(qf[j].y, klds[e + 1][k], partial);
            partial = fmaf(qf[j].z, klds[e + 2][k], partial);
            partial = fmaf(qf[j].w, klds[e + 3][k], partial);
        }
        float qk = partial + __shfl_xor(partial, 1);   // both halves
        // max over the 32 k-values (duplicated in lane pairs): xor-tree
        float M = qk;
#pragma unroll
        for (int o = 2; o < 64; o <<= 1) M = fmaxf(M, __shfl_xor(M, o));
        float ev = expf(0.125f * (qk - M));
        float den = ev;
#pragma unroll
        for (int o = 2; o < 64; o <<= 1) den += __shfl_xor(den, o);
        float as_ = (ev / den) * scale;                // A_s for my k
        if (!hh) aslds[wid][k] = as_;
        // PV: lane = d; aslds reads broadcast, vlds 2-way
        float acc = 0.f;
#pragma unroll
        for (int j = 0; j < cK; ++j)
            acc = fmaf(aslds[wid][j], vlds[j][lane], acc);
        acc += vbgd;
        int qidx = nh * cL + l;
        out[(((size_t)n * cL + l) * cH + h) * cD + lane] = acc;   // (N,L,H,D)
        if (lane < cK) {
            out[off1 + (size_t)qidx * cK + lane] = stf;           // sparse_index
            out[off2 + (size_t)qidx * cK + lane] = aslds[wid][lane]; // A_topk
        }
    }
}

// ---------------- launch -------------------------------------------------
extern "C" void kernel_launch(void* const* d_in, const int* in_sizes, int n_in,
                              void* d_out, int out_size, void* d_ws, size_t ws_size,
                              hipStream_t stream)
{
    (void)in_sizes; (void)n_in; (void)out_size; (void)ws_size;
    const float* q      = (const float*)d_in[0];
    const float* key    = (const float*)d_in[1];
    const float* val    = (const float*)d_in[2];
    const float* planes = (const float*)d_in[3];
    char* w = (char*)d_ws;
    unsigned int* bits = (unsigned int*)w;  w += (size_t)cN * cH * cL * 4;
    int*   cl     = (int*)w;                w += (size_t)cN * cH * cL * 4;
    int*   counts = (int*)w;                w += (size_t)cN * cH * cC * 4;
    float* abk    = (float*)w;              w += (size_t)cN * cH * cC * 4;
    float* Qg     = (float*)w;              w += (size_t)cN * cH * cC * cE * 4;
    float* vbg    = (float*)w;              w += (size_t)cN * cH * cC * cD * 4;
    int*   topkp  = (int*)w;                w += (size_t)cN * cH * cC * cK * 4;
    float* QK     = (float*)w;              w += (size_t)cNH * cC * cS * 4;      // 16 MB (QK -> P in place)
    float* part   = (float*)w;              w += (size_t)SK * cNH * cC * cD * 4; // 4 MB
    unsigned int* cent = (unsigned int*)w;  w += (size_t)cNH * cC * 4;           // 8 KB
    int*   partial = (int*)w;               w += (size_t)cNH * TILES * HW * 4;   // 2.2 MB
    int*   mlist  = (int*)w;                w += (size_t)cNH * cL * 4;           // 128 KB
    int*   moff   = (int*)w;                w += (size_t)cNH * cC * 4;           // 8 KB
    float* out = (float*)d_out;

    k_bits   <<<(cN * cH * cL) / 256, 256, 0, stream>>>(q, planes, bits);
    k_init   <<<(cNH * cC) / 256, 256, 0, stream>>>(bits, cent);
    for (int it = 0; it < cIT; ++it) {
        k_assign <<<cNH * TILES, 256, 0, stream>>>(bits, cent, partial, cl, 0);
        k_update <<<cNH, 128, 0, stream>>>(partial, cent, counts, moff, 0);
    }
    k_assign <<<cNH * TILES, 256, 0, stream>>>(bits, cent, partial, cl, 1);
    k_update <<<cNH, 128, 0, stream>>>(partial, cent, counts, moff, 1);
    k_rank   <<<cNH * TILES, 256, 0, stream>>>(cl, partial, moff, mlist);
    k_qg     <<<cNH * cC, 64, 0, stream>>>(q, mlist, moff, counts, Qg);
    k_qk_gemm<<<cNH * 16, 256, 0, stream>>>(key, Qg, QK);
    k_sel    <<<cNH * cC, 256, 0, stream>>>(QK, topkp, abk);
    k_pv     <<<cNH * SK * 2, 256, 0, stream>>>(QK, val, part);
    k_red    <<<(cNH * cC * cD) / 256, 256, 0, stream>>>(part, vbg);
    k_out    <<<cNH * cC * OSPLIT, 256, 0, stream>>>(q, key, val, mlist, moff,
                                                     counts, abk, vbg, topkp, out);
}

// Round 10
// 374.563 us; speedup vs baseline: 1.2084x; 1.1135x over previous
//
#include <hip/hip_runtime.h>
#include <math.h>

constexpr int cN = 2, cH = 8, cL = 2048, cS = 2048, cE = 64, cD = 64;
constexpr int cC = 128, cK = 32, cB = 32, cIT = 10;
constexpr int cNH = cN * cH;          // 16
constexpr int SK = 8;                 // split-K factor for PV
constexpr int CHUNK = cS / SK;        // 256 s per split
constexpr int TILES = 8;              // point tiles per nh in k_assign
constexpr int HW = cC * 33;           // partial hist words: sbs[128][32] + scnt[128]
constexpr int OSPLIT = 2;             // blocks per cluster in k_out
// TEMP = 1/sqrt(64) = 0.125 exactly

// ---------------- Kernel 1: LSH bits -------------------------------------
__global__ __launch_bounds__(256)
void k_bits(const float* __restrict__ q, const float* __restrict__ planes,
            unsigned int* __restrict__ bits)
{
    __shared__ float pl[cB * (cE + 1)];
    int tid = threadIdx.x;
    for (int i = tid; i < cB * (cE + 1); i += 256) pl[i] = planes[i];
    __syncthreads();
    int idx = blockIdx.x * 256 + tid;           // (n*H + h)*L + l
    int l = idx % cL, h = (idx / cL) % cH, n = idx / (cL * cH);
    const float* qr = q + (((size_t)n * cL + l) * cH + h) * cE;
    float qv[cE];
#pragma unroll
    for (int e4 = 0; e4 < cE / 4; ++e4) {
        float4 f = ((const float4*)qr)[e4];
        qv[4*e4+0] = f.x; qv[4*e4+1] = f.y; qv[4*e4+2] = f.z; qv[4*e4+3] = f.w;
    }
    unsigned int w = 0;
    for (int b = 0; b < cB; ++b) {
        float acc = 0.f;
#pragma unroll
        for (int e = 0; e < cE; ++e) acc = fmaf(qv[e], pl[b * (cE + 1) + e], acc);
        acc += pl[b * (cE + 1) + cE];
        if (acc > 0.f) w |= (1u << b);
    }
    bits[idx] = w;
}

// ---------------- Kernel 2a: initial centroids ---------------------------
__global__ __launch_bounds__(256)
void k_init(const unsigned int* __restrict__ bits, unsigned int* __restrict__ cent)
{
    int i = blockIdx.x * 256 + threadIdx.x;     // nh*128 + c
    int c = i & 127, nh = i >> 7;
    // idx0 = linspace(0, L-1, C).astype(int32): floor(c*2047/127), endpoint exact
    int i0 = (int)(((double)c * 2047.0) / 127.0);
    cent[i] = bits[(size_t)nh * cL + i0];
}

// ---------------- Kernel 2b: assignment + partial histograms -------------
// grid = 16 nh x 8 tiles = 128 blocks, 256 threads (1 point each)
__global__ __launch_bounds__(256)
void k_assign(const unsigned int* __restrict__ bits,
              const unsigned int* __restrict__ cent,
              int* __restrict__ partial, int* __restrict__ cl, int write_cl)
{
    __shared__ unsigned int scb[cC] __attribute__((aligned(16)));
    __shared__ int hist[HW];      // [c*32+b] bitsums, [4096+c] counts
    int tid = threadIdx.x;
    int lane = tid & 63;
    int tile = blockIdx.x & (TILES - 1), nh = blockIdx.x / TILES;
    if (tid < cC) scb[tid] = cent[nh * cC + tid];
    for (int i = tid; i < HW; i += 256) hist[i] = 0;
    int l = tile * 256 + tid;
    unsigned int w = bits[(size_t)nh * cL + l];
    // per-lane bit ballots over this wave's 64 points (lane b&31 keeps bit b)
    unsigned long long mymb = 0ull;
#pragma unroll
    for (int b = 0; b < cB; ++b) {
        unsigned long long m = __ballot((w >> b) & 1u);
        if ((lane & 31) == b) mymb = m;
    }
    __syncthreads();
    const uint4* scb4 = (const uint4*)scb;
    // packed key = (hamming<<8)|c -> min = lowest dist, tie lowest c
    int best = 0x7fffffff;
    for (int c4 = 0; c4 < cC / 4; ++c4) {
        uint4 cb = scb4[c4];
        int c = c4 * 4;
        best = min(best, (__popc(w ^ cb.x) << 8) | c);
        best = min(best, (__popc(w ^ cb.y) << 8) | (c + 1));
        best = min(best, (__popc(w ^ cb.z) << 8) | (c + 2));
        best = min(best, (__popc(w ^ cb.w) << 8) | (c + 3));
    }
    int bc = best & 255;
    if (write_cl) cl[(size_t)nh * cL + l] = bc;
    // wave-aggregated histogram into LDS (integer atomics: deterministic)
    for (int c = 0; c < cC; ++c) {
        unsigned long long m = __ballot(bc == c);
        if (m) {
            if (lane < cB) {
                int contrib = __popcll(m & mymb);
                if (contrib) atomicAdd(&hist[c * 32 + lane], contrib);
            }
            if (lane == 63) atomicAdd(&hist[4096 + c], __popcll(m));
        }
    }
    __syncthreads();
    int* dst = partial + (size_t)(nh * TILES + tile) * HW;
    for (int i = tid; i < HW; i += 256) dst[i] = hist[i];
}

// ---------------- Kernel 2c: centroid update / final counts+moff ---------
// grid = 16 blocks x 128 threads (thread = cluster)
__global__ __launch_bounds__(128)
void k_update(const int* __restrict__ partial, unsigned int* __restrict__ cent,
              int* __restrict__ counts, int* __restrict__ moff, int mode)
{
    __shared__ int scn[cC];
    int c = threadIdx.x, nh = blockIdx.x;
    int cnt = 0;
    int bs[cB];
#pragma unroll
    for (int b = 0; b < cB; ++b) bs[b] = 0;
    for (int t = 0; t < TILES; ++t) {
        const int* p = partial + (size_t)(nh * TILES + t) * HW;
        cnt += p[4096 + c];
#pragma unroll
        for (int b = 0; b < cB; ++b) bs[b] += p[c * 32 + b];
    }
    if (mode == 0) {
        if (cnt > 0) {                       // keep old centroid if empty
            unsigned int nw = 0;
#pragma unroll
            for (int b = 0; b < cB; ++b)
                if (2 * bs[b] > cnt) nw |= (1u << b);
            cent[nh * cC + c] = nw;
        }
    } else {
        counts[nh * cC + c] = cnt;
        scn[c] = cnt;
        __syncthreads();
        if (c == 0) {
            int run = 0;
            for (int i = 0; i < cC; ++i) { int v = scn[i]; scn[i] = run; run += v; }
        }
        __syncthreads();
        moff[nh * cC + c] = scn[c];          // exclusive cluster prefix
    }
}

// ---------------- Kernel 2d: parallel stable counting-sort ranks ---------
// grid = 16 nh x 8 tiles = 128 blocks, 256 threads (1 point each)
// pos = moff[nh][c] + sum_{t'<tile} partial[t'].count[c] + in-tile stable rank
__global__ __launch_bounds__(256)
void k_rank(const int* __restrict__ cl, const int* __restrict__ partial,
            const int* __restrict__ moff, int* __restrict__ mlist)
{
    __shared__ int pre[cC];
    __shared__ int wcnt[4][cC];
    int tid = threadIdx.x, lane = tid & 63, wid = tid >> 6;
    int tile = blockIdx.x & (TILES - 1), nh = blockIdx.x / TILES;
    if (tid < cC) {
        int s = 0;
        for (int t = 0; t < tile; ++t)
            s += partial[(size_t)(nh * TILES + t) * HW + 4096 + tid];
        pre[tid] = s + moff[nh * cC + tid];
    }
    int l = tile * 256 + tid;
    int bc = cl[(size_t)nh * cL + l];
    unsigned long long ltmask = (1ull << lane) - 1ull;   // lanes below me
    int myrank = 0;
    for (int c = 0; c < cC; ++c) {
        unsigned long long m = __ballot(bc == c);
        if (lane == 0) wcnt[wid][c] = __popcll(m);
        if (bc == c) myrank = __popcll(m & ltmask);
    }
    __syncthreads();
    int off = pre[bc] + myrank;
    for (int w = 0; w < 4; ++w)
        if (w < wid) off += wcnt[w][bc];
    mlist[(size_t)nh * cL + off] = l;
}

// ---------------- Kernel 3: cluster-mean queries Qg ----------------------
// one block (64 lanes = e) per (nh,c); dense member list, batched loads,
// strict ascending-l single-accumulator chain (bit-exact vs np GEMM)
__global__ __launch_bounds__(64)
void k_qg(const float* __restrict__ q, const int* __restrict__ mlist,
          const int* __restrict__ moff, const int* __restrict__ counts,
          float* __restrict__ Qg)
{
    int b = blockIdx.x;                 // nh*cC + c
    int nh = b >> 7;
    int h = nh % cH, n = nh / cH;
    int lane = threadIdx.x;
    int off = moff[b];
    int cnt = counts[b];
    const int* ml = mlist + (size_t)nh * cL + off;
    const float* qb = q + ((size_t)n * cL * cH + h) * cE + lane;
    float acc = 0.f;
    int j = 0;
    for (; j + 4 <= cnt; j += 4) {
        int i0 = ml[j], i1 = ml[j + 1], i2 = ml[j + 2], i3 = ml[j + 3];
        float v0 = qb[(size_t)i0 * cH * cE];
        float v1 = qb[(size_t)i1 * cH * cE];
        float v2 = qb[(size_t)i2 * cH * cE];
        float v3 = qb[(size_t)i3 * cH * cE];
        acc += v0; acc += v1; acc += v2; acc += v3;    // in-order chain
    }
    for (; j < cnt; ++j) acc += qb[(size_t)ml[j] * cH * cE];
    float cs = (float)(cnt > 0 ? cnt : 1);
    Qg[(size_t)b * cE + lane] = acc / cs;
}

// ---------------- Kernel 4a: QK = Qg . k^T  (tiled GEMM, exact chains) ---
// grid = nh(16) x s-tiles(16 of 128); block 256 = 16 ty (c) x 16 tx (s)
__global__ __launch_bounds__(256)
void k_qk_gemm(const float* __restrict__ key, const float* __restrict__ Qg,
               float* __restrict__ QK)
{
    __shared__ float qgT[cE][cC + 2];      // [e][c]
    __shared__ float kT[cE][128 + 2];      // [e][s_local]
    int tid = threadIdx.x;
    int bs = blockIdx.x & 15;              // s-tile
    int nh = blockIdx.x >> 4;
    int h = nh % cH, n = nh / cH;
    const float4* qsrc = (const float4*)(Qg + (size_t)nh * cC * cE);
#pragma unroll
    for (int i = 0; i < 8; ++i) {
        int f = tid + 256 * i;
        int c = f >> 4, e4 = (f & 15) << 2;
        float4 v = qsrc[f];
        qgT[e4+0][c] = v.x; qgT[e4+1][c] = v.y; qgT[e4+2][c] = v.z; qgT[e4+3][c] = v.w;
    }
    const float* kb = key + (size_t)n * cS * cH * cE + (size_t)h * cE;
    int s0 = bs * 128;
#pragma unroll
    for (int i = 0; i < 8; ++i) {
        int f = tid + 256 * i;
        int s = f >> 4, e4 = (f & 15) << 2;
        float4 v = *(const float4*)(kb + (size_t)(s0 + s) * (cH * cE) + e4);
        kT[e4+0][s] = v.x; kT[e4+1][s] = v.y; kT[e4+2][s] = v.z; kT[e4+3][s] = v.w;
    }
    __syncthreads();
    int tx = tid & 15, ty = tid >> 4;
    float acc[8][8];
#pragma unroll
    for (int i = 0; i < 8; ++i)
#pragma unroll
        for (int j = 0; j < 8; ++j) acc[i][j] = 0.f;
    for (int e = 0; e < cE; ++e) {
        float qv[8], kv[8];
#pragma unroll
        for (int i = 0; i < 8; ++i) qv[i] = qgT[e][ty + 16 * i];
#pragma unroll
        for (int j = 0; j < 8; ++j) kv[j] = kT[e][tx + 16 * j];
#pragma unroll
        for (int i = 0; i < 8; ++i)
#pragma unroll
            for (int j = 0; j < 8; ++j)
                acc[i][j] = fmaf(qv[i], kv[j], acc[i][j]);   // ascending-e chain
    }
    float* dst = QK + (size_t)nh * cC * cS + s0;
#pragma unroll
    for (int i = 0; i < 8; ++i)
#pragma unroll
        for (int j = 0; j < 8; ++j)
            dst[(size_t)(ty + 16 * i) * cS + tx + 16 * j] = acc[i][j];
}

// ---------------- Kernel 4b: radix-select top-32 + softmax -> P ----------
// one block (256 threads) per (n,h,c) row; row register-resident (8/thread).
// Selection is integer-exact on monotone keys -> topk indices bit-identical
// to the iterative (value desc, index asc) semantics.
__global__ __launch_bounds__(256)
void k_sel(float* __restrict__ QK, int* __restrict__ topk,
           float* __restrict__ abk)
{
    __shared__ int sbins[4 * 257];        // 4 wave copies, bank-staggered
    __shared__ int ired[4];
    __shared__ float fred[4];
    __shared__ unsigned skey[cK];
    __shared__ float sval[cK];
    __shared__ int sidx[cK];
    __shared__ int stopk[cK];
    __shared__ int sDig, sRem, scnt, sTieTot;
    __shared__ float sM;
    int tid = threadIdx.x, lane = tid & 63, wid = tid >> 6;
    int b = blockIdx.x;                  // (n*H + h)*C + c
    float* qrow = QK + (size_t)b * cS;
    float v[8]; unsigned key[8];
#pragma unroll
    for (int j = 0; j < 8; ++j) {
        float f = qrow[tid + j * 256];
        v[j] = f;
        unsigned u = __float_as_uint(f);
        key[j] = (u & 0x80000000u) ? ~u : (u | 0x80000000u);   // monotone map
    }
    if (tid == 0) { sRem = cK; scnt = 0; }
    unsigned pfx = 0;
    // 4x8-bit radix select for the 32nd-largest key
    for (int pass = 0; pass < 4; ++pass) {
        int sh = 24 - 8 * pass;
        for (int i = tid; i < 4 * 257; i += 256) sbins[i] = 0;
        __syncthreads();
        int rem = sRem;
#pragma unroll
        for (int j = 0; j < 8; ++j) {
            bool cand = (pass == 0) || ((key[j] >> (sh + 8)) == pfx);
            if (cand) atomicAdd(&sbins[wid * 257 + ((key[j] >> sh) & 255)], 1);
        }
        __syncthreads();
        if (wid == 0) {
            int d0 = lane * 4;
            int c0 = sbins[d0] + sbins[257 + d0] + sbins[514 + d0] + sbins[771 + d0];
            int c1 = sbins[d0+1] + sbins[257+d0+1] + sbins[514+d0+1] + sbins[771+d0+1];
            int c2 = sbins[d0+2] + sbins[257+d0+2] + sbins[514+d0+2] + sbins[771+d0+2];
            int c3 = sbins[d0+3] + sbins[257+d0+3] + sbins[514+d0+3] + sbins[771+d0+3];
            int tot = c0 + c1 + c2 + c3;
            int incl = tot;                           // backward inclusive scan
#pragma unroll
            for (int off = 1; off < 64; off <<= 1) {
                int o = __shfl_down(incl, off);
                if (lane + off < 64) incl += o;
            }
            int sufHi = incl - tot;                   // count with digit > my range
            int G3 = sufHi, G2 = sufHi + c3, G1 = G2 + c2, G0 = G1 + c1;
            int hit = -1, hG = 0;
            if (G0 < rem && rem <= G0 + c0) { hit = d0 + 0; hG = G0; }
            if (G1 < rem && rem <= G1 + c1) { hit = d0 + 1; hG = G1; }
            if (G2 < rem && rem <= G2 + c2) { hit = d0 + 2; hG = G2; }
            if (G3 < rem && rem <= G3 + c3) { hit = d0 + 3; hG = G3; }
            unsigned long long m = __ballot(hit >= 0);
            int src = __ffsll((long long)m) - 1;
            int dsel = __shfl(hit, src);
            int Gsel = __shfl(hG, src);
            if (lane == 0) { sDig = dsel; sRem = rem - Gsel; }
        }
        __syncthreads();
        pfx = (pfx << 8) | (unsigned)sDig;
    }
    unsigned T = pfx;
    int need = sRem;                      // ties at T to take (smallest indices)
    // count ties
    int myT = 0;
#pragma unroll
    for (int j = 0; j < 8; ++j) myT += (key[j] == T);
#pragma unroll
    for (int off = 1; off < 64; off <<= 1) myT += __shfl_xor(myT, off);
    if (lane == 0) ired[wid] = myT;
    __syncthreads();
    int tieTot = ((ired[0] + ired[1]) + ired[2]) + ired[3];
    int tieCut = 0x7fffffff;
    if (tieTot != need) {                 // rare: pick need-th smallest tie index
        int last = -1;
        for (int t = 0; t < need; ++t) {
            int mymin = 0x7fffffff;
#pragma unroll
            for (int j = 0; j < 8; ++j) {
                int idx = tid + j * 256;
                if (key[j] == T && idx > last) mymin = min(mymin, idx);
            }
#pragma unroll
            for (int off = 1; off < 64; off <<= 1)
                mymin = min(mymin, __shfl_xor(mymin, off));
            __syncthreads();              // protect ired reuse
            if (lane == 0) ired[wid] = mymin;
            __syncthreads();
            last = min(min(ired[0], ired[1]), min(ired[2], ired[3]));
        }
        tieCut = last;
    }
    // gather selected (exactly 32) into LDS; order arbitrary, rank fixes it
    __syncthreads();
    int selm = 0;
#pragma unroll
    for (int j = 0; j < 8; ++j) {
        int idx = tid + j * 256;
        bool s_ = (key[j] > T) || (key[j] == T && idx <= tieCut);
        if (s_) {
            int slot = atomicAdd(&scnt, 1);
            skey[slot] = key[j]; sidx[slot] = idx; sval[slot] = v[j];
            selm |= (1 << j);
        }
    }
    __syncthreads();
    // rank the 32 by (value desc, index asc); deterministic
    if (tid < cK) {
        unsigned kt = skey[tid]; int it = sidx[tid];
        int rank = 0;
#pragma unroll
        for (int j = 0; j < cK; ++j)
            rank += (skey[j] > kt) || (skey[j] == kt && sidx[j] < it);
        stopk[rank] = it;
        if (rank == 0) sM = sval[tid];    // row max (exact)
    }
    __syncthreads();
    if (tid < cK) topk[(size_t)b * cK + tid] = stopk[tid];
    // softmax (float outputs only; loose tolerance)
    float M = sM;
    float e8[8]; float ps = 0.f;
#pragma unroll
    for (int j = 0; j < 8; ++j) { e8[j] = expf(0.125f * (v[j] - M)); ps += e8[j]; }
#pragma unroll
    for (int off = 1; off < 64; off <<= 1) ps += __shfl_xor(ps, off);
    if (lane == 0) fred[wid] = ps;
    __syncthreads();
    float den = ((fred[0] + fred[1]) + fred[2]) + fred[3];
    float ab = 0.f;
#pragma unroll
    for (int j = 0; j < 8; ++j) {
        float P = (selm & (1 << j)) ? 0.f : e8[j] / den;
        ab += P;
        qrow[tid + j * 256] = P;
    }
#pragma unroll
    for (int off = 1; off < 64; off <<= 1) ab += __shfl_xor(ab, off);
    __syncthreads();                      // protect fred reuse
    if (lane == 0) fred[wid] = ab;
    __syncthreads();
    if (tid == 0) abk[b] = ((fred[0] + fred[1]) + fred[2]) + fred[3];
}

// ---------------- Kernel 4c: Vb_g partials = P . v (split-K GEMM) --------
// grid = nh(16) x sk(8) x ch(2);  block 256 = 16 ty (c) x 16 tx (d4)
__global__ __launch_bounds__(256)
void k_pv(const float* __restrict__ P, const float* __restrict__ val,
          float* __restrict__ part)
{
    __shared__ float pT[64][64 + 2];       // [c_local][s_sub]
    __shared__ float vT[64][cD + 4];       // [s_sub][d]
    int tid = threadIdx.x;
    int ch = blockIdx.x & 1;
    int sk = (blockIdx.x >> 1) & 7;
    int nh = blockIdx.x >> 4;
    int h = nh % cH, n = nh / cH;
    int tx = tid & 15, ty = tid >> 4;
    float acc[4][4];
#pragma unroll
    for (int i = 0; i < 4; ++i)
#pragma unroll
        for (int j = 0; j < 4; ++j) acc[i][j] = 0.f;
    const float* pb = P + ((size_t)nh * cC + ch * 64) * cS;
    const float* vb = val + (size_t)n * cS * cH * cD + (size_t)h * cD;
    for (int sub = 0; sub < CHUNK / 64; ++sub) {
        int s0 = sk * CHUNK + sub * 64;
#pragma unroll
        for (int i = 0; i < 4; ++i) {
            int f = tid + 256 * i;
            int c = f >> 4, s4 = (f & 15) << 2;
            float4 v = *(const float4*)(pb + (size_t)c * cS + s0 + s4);
            pT[c][s4+0] = v.x; pT[c][s4+1] = v.y; pT[c][s4+2] = v.z; pT[c][s4+3] = v.w;
        }
#pragma unroll
        for (int i = 0; i < 4; ++i) {
            int f = tid + 256 * i;
            int ss = f >> 4, d4 = (f & 15) << 2;
            float4 v = *(const float4*)(vb + (size_t)(s0 + ss) * (cH * cD) + d4);
            vT[ss][d4+0] = v.x; vT[ss][d4+1] = v.y; vT[ss][d4+2] = v.z; vT[ss][d4+3] = v.w;
        }
        __syncthreads();
        for (int ss = 0; ss < 64; ++ss) {
            float pv[4];
#pragma unroll
            for (int i = 0; i < 4; ++i) pv[i] = pT[ty + 16 * i][ss];
            float4 vv = *(const float4*)&vT[ss][tx * 4];
#pragma unroll
            for (int i = 0; i < 4; ++i) {
                acc[i][0] = fmaf(pv[i], vv.x, acc[i][0]);
                acc[i][1] = fmaf(pv[i], vv.y, acc[i][1]);
                acc[i][2] = fmaf(pv[i], vv.z, acc[i][2]);
                acc[i][3] = fmaf(pv[i], vv.w, acc[i][3]);
            }
        }
        __syncthreads();
    }
    float* dst = part + (((size_t)sk * cNH + nh) * cC + ch * 64) * cD;
#pragma unroll
    for (int i = 0; i < 4; ++i) {
        float4 o; o.x = acc[i][0]; o.y = acc[i][1]; o.z = acc[i][2]; o.w = acc[i][3];
        *(float4*)(dst + (size_t)(ty + 16 * i) * cD + tx * 4) = o;
    }
}

// ---------------- Kernel 4d: reduce split-K partials ---------------------
__global__ __launch_bounds__(256)
void k_red(const float* __restrict__ part, float* __restrict__ vbg)
{
    int i = blockIdx.x * 256 + threadIdx.x;      // over 16*128*64 = 131072
    float acc = 0.f;
    for (int sk = 0; sk < SK; ++sk) acc += part[(size_t)sk * (cNH * cC * cD) + i];
    vbg[i] = acc;
}

// ---------------- Kernel 5: per-cluster epilogue (lane-parallel) ---------
__global__ __launch_bounds__(256)
void k_out(const float* __restrict__ q, const float* __restrict__ key,
           const float* __restrict__ val, const int* __restrict__ mlist,
           const int* __restrict__ moff, const int* __restrict__ counts,
           const float* __restrict__ abk, const float* __restrict__ vbg,
           const int* __restrict__ topk, float* __restrict__ out)
{
    __shared__ float klds[cE][cK + 1];   // [e][k]: 2-way alias (free)
    __shared__ float vlds[cK][cD + 1];
    __shared__ float aslds[4][cK];
    __shared__ int   st[cK];
    int tid = threadIdx.x, lane = tid & 63, wid = tid >> 6;
    int bb = blockIdx.x;
    int p = bb & (OSPLIT - 1);
    int b = bb / OSPLIT;                // nh*cC + c
    int nh = b >> 7;
    int h = nh % cH, n = nh / cH;
    if (tid < cK) st[tid] = topk[(size_t)b * cK + tid];
    __syncthreads();
    const float* kb = key + ((size_t)n * cS * cH + h) * cE;
    const float* vb = val + ((size_t)n * cS * cH + h) * cD;
    for (int r = wid; r < cK; r += 4) {
        int t = st[r];
        klds[lane][r] = kb[(size_t)t * cH * cE + lane];   // transposed
        vlds[r][lane] = vb[(size_t)t * cH * cD + lane];
    }
    __syncthreads();
    int cnt = counts[b];
    int off = moff[b];
    float scale = 1.0f - abk[b];
    float vbgd = vbg[(size_t)b * cD + lane];
    float stf = (lane < cK) ? (float)st[lane] : 0.f;
    const int* ml = mlist + (size_t)nh * cL + off;
    const size_t off1 = (size_t)cN * cL * cH * cD;
    const size_t off2 = off1 + (size_t)cN * cH * cL * cK;
    int k = lane >> 1, hh = lane & 1;
    for (int m = p * 4 + wid; m < cnt; m += 4 * OSPLIT) {   // wave-uniform loop
        int l = ml[m];
        const float* qrow = q + (((size_t)n * cL + l) * cH + h) * cE + hh * 32;
        float4 qf[8];
#pragma unroll
        for (int j = 0; j < 8; ++j) qf[j] = ((const float4*)qrow)[j];
        float partial = 0.f;
#pragma unroll
        for (int j = 0; j < 8; ++j) {
            int e = hh * 32 + 4 * j;
            partial = fmaf(qf[j].x, klds[e + 0][k], partial);
            partial = fmaf(qf[j].y, klds[e + 1][k], partial);
            partial = fmaf(qf[j].z, klds[e + 2][k], partial);
            partial = fmaf(qf[j].w, klds[e + 3][k], partial);
        }
        float qk = partial + __shfl_xor(partial, 1);
        float M = qk;
#pragma unroll
        for (int o = 2; o < 64; o <<= 1) M = fmaxf(M, __shfl_xor(M, o));
        float ev = expf(0.125f * (qk - M));
        float den = ev;
#pragma unroll
        for (int o = 2; o < 64; o <<= 1) den += __shfl_xor(den, o);
        float as_ = (ev / den) * scale;
        if (!hh) aslds[wid][k] = as_;
        float acc = 0.f;
#pragma unroll
        for (int j = 0; j < cK; ++j)
            acc = fmaf(aslds[wid][j], vlds[j][lane], acc);
        acc += vbgd;
        int qidx = nh * cL + l;
        out[(((size_t)n * cL + l) * cH + h) * cD + lane] = acc;   // (N,L,H,D)
        if (lane < cK) {
            out[off1 + (size_t)qidx * cK + lane] = stf;           // sparse_index
            out[off2 + (size_t)qidx * cK + lane] = aslds[wid][lane]; // A_topk
        }
    }
}

// ---------------- launch -------------------------------------------------
extern "C" void kernel_launch(void* const* d_in, const int* in_sizes, int n_in,
                              void* d_out, int out_size, void* d_ws, size_t ws_size,
                              hipStream_t stream)
{
    (void)in_sizes; (void)n_in; (void)out_size; (void)ws_size;
    const float* q      = (const float*)d_in[0];
    const float* key    = (const float*)d_in[1];
    const float* val    = (const float*)d_in[2];
    const float* planes = (const float*)d_in[3];
    char* w = (char*)d_ws;
    unsigned int* bits = (unsigned int*)w;  w += (size_t)cN * cH * cL * 4;
    int*   cl     = (int*)w;                w += (size_t)cN * cH * cL * 4;
    int*   counts = (int*)w;                w += (size_t)cN * cH * cC * 4;
    float* abk    = (float*)w;              w += (size_t)cN * cH * cC * 4;
    float* Qg     = (float*)w;              w += (size_t)cN * cH * cC * cE * 4;
    float* vbg    = (float*)w;              w += (size_t)cN * cH * cC * cD * 4;
    int*   topkp  = (int*)w;                w += (size_t)cN * cH * cC * cK * 4;
    float* QK     = (float*)w;              w += (size_t)cNH * cC * cS * 4;      // 16 MB (QK -> P in place)
    float* part   = (float*)w;              w += (size_t)SK * cNH * cC * cD * 4; // 4 MB
    unsigned int* cent = (unsigned int*)w;  w += (size_t)cNH * cC * 4;           // 8 KB
    int*   partial = (int*)w;               w += (size_t)cNH * TILES * HW * 4;   // 2.2 MB
    int*   mlist  = (int*)w;                w += (size_t)cNH * cL * 4;           // 128 KB
    int*   moff   = (int*)w;                w += (size_t)cNH * cC * 4;           // 8 KB
    float* out = (float*)d_out;

    k_bits   <<<(cN * cH * cL) / 256, 256, 0, stream>>>(q, planes, bits);
    k_init   <<<(cNH * cC) / 256, 256, 0, stream>>>(bits, cent);
    for (int it = 0; it < cIT; ++it) {
        k_assign <<<cNH * TILES, 256, 0, stream>>>(bits, cent, partial, cl, 0);
        k_update <<<cNH, 128, 0, stream>>>(partial, cent, counts, moff, 0);
    }
    k_assign <<<cNH * TILES, 256, 0, stream>>>(bits, cent, partial, cl, 1);
    k_update <<<cNH, 128, 0, stream>>>(partial, cent, counts, moff, 1);
    k_rank   <<<cNH * TILES, 256, 0, stream>>>(cl, partial, moff, mlist);
    k_qg     <<<cNH * cC, 64, 0, stream>>>(q, mlist, moff, counts, Qg);
    k_qk_gemm<<<cNH * 16, 256, 0, stream>>>(key, Qg, QK);
    k_sel    <<<cNH * cC, 256, 0, stream>>>(QK, topkp, abk);
    k_pv     <<<cNH * SK * 2, 256, 0, stream>>>(QK, val, part);
    k_red    <<<(cNH * cC * cD) / 256, 256, 0, stream>>>(part, vbg);
    k_out    <<<cNH * cC * OSPLIT, 256, 0, stream>>>(q, key, val, mlist, moff,
                                                     counts, abk, vbg, topkp, out);
}

// Round 11
// 373.408 us; speedup vs baseline: 1.2122x; 1.0031x over previous
//
#include <hip/hip_runtime.h>
#include <math.h>

constexpr int cN = 2, cH = 8, cL = 2048, cS = 2048, cE = 64, cD = 64;
constexpr int cC = 128, cK = 32, cB = 32, cIT = 10;
constexpr int cNH = cN * cH;          // 16
constexpr int SK = 8;                 // split-K factor for PV
constexpr int CHUNK = cS / SK;        // 256 s per split
constexpr int TILES = 8;              // point tiles per nh in k_assign
constexpr int HW = cC * 33;           // partial hist words: sbs[128][32] + scnt[128]
// TEMP = 1/sqrt(64) = 0.125 exactly

// ---------------- Kernel 1: LSH bits -------------------------------------
__global__ __launch_bounds__(256)
void k_bits(const float* __restrict__ q, const float* __restrict__ planes,
            unsigned int* __restrict__ bits)
{
    __shared__ float pl[cB * (cE + 1)];
    int tid = threadIdx.x;
    for (int i = tid; i < cB * (cE + 1); i += 256) pl[i] = planes[i];
    __syncthreads();
    int idx = blockIdx.x * 256 + tid;           // (n*H + h)*L + l
    int l = idx % cL, h = (idx / cL) % cH, n = idx / (cL * cH);
    const float* qr = q + (((size_t)n * cL + l) * cH + h) * cE;
    float qv[cE];
#pragma unroll
    for (int e4 = 0; e4 < cE / 4; ++e4) {
        float4 f = ((const float4*)qr)[e4];
        qv[4*e4+0] = f.x; qv[4*e4+1] = f.y; qv[4*e4+2] = f.z; qv[4*e4+3] = f.w;
    }
    unsigned int w = 0;
    for (int b = 0; b < cB; ++b) {
        float acc = 0.f;
#pragma unroll
        for (int e = 0; e < cE; ++e) acc = fmaf(qv[e], pl[b * (cE + 1) + e], acc);
        acc += pl[b * (cE + 1) + cE];
        if (acc > 0.f) w |= (1u << b);
    }
    bits[idx] = w;
}

// ---------------- Kernel 2a: initial centroids ---------------------------
__global__ __launch_bounds__(256)
void k_init(const unsigned int* __restrict__ bits, unsigned int* __restrict__ cent)
{
    int i = blockIdx.x * 256 + threadIdx.x;     // nh*128 + c
    int c = i & 127, nh = i >> 7;
    // idx0 = linspace(0, L-1, C).astype(int32): floor(c*2047/127), endpoint exact
    int i0 = (int)(((double)c * 2047.0) / 127.0);
    cent[i] = bits[(size_t)nh * cL + i0];
}

// ---------------- Kernel 2b: assignment + partial histograms -------------
// grid = 16 nh x 8 tiles = 128 blocks, 256 threads (1 point each)
__global__ __launch_bounds__(256)
void k_assign(const unsigned int* __restrict__ bits,
              const unsigned int* __restrict__ cent,
              int* __restrict__ partial, int* __restrict__ cl, int write_cl)
{
    __shared__ unsigned int scb[cC] __attribute__((aligned(16)));
    __shared__ int hist[HW];      // [c*32+b] bitsums, [4096+c] counts
    int tid = threadIdx.x;
    int lane = tid & 63;
    int tile = blockIdx.x & (TILES - 1), nh = blockIdx.x / TILES;
    if (tid < cC) scb[tid] = cent[nh * cC + tid];
    for (int i = tid; i < HW; i += 256) hist[i] = 0;
    int l = tile * 256 + tid;
    unsigned int w = bits[(size_t)nh * cL + l];
    // per-lane bit ballots over this wave's 64 points (lane b&31 keeps bit b)
    unsigned long long mymb = 0ull;
#pragma unroll
    for (int b = 0; b < cB; ++b) {
        unsigned long long m = __ballot((w >> b) & 1u);
        if ((lane & 31) == b) mymb = m;
    }
    __syncthreads();
    const uint4* scb4 = (const uint4*)scb;
    // packed key = (hamming<<8)|c -> min = lowest dist, tie lowest c
    int best = 0x7fffffff;
    for (int c4 = 0; c4 < cC / 4; ++c4) {
        uint4 cb = scb4[c4];
        int c = c4 * 4;
        best = min(best, (__popc(w ^ cb.x) << 8) | c);
        best = min(best, (__popc(w ^ cb.y) << 8) | (c + 1));
        best = min(best, (__popc(w ^ cb.z) << 8) | (c + 2));
        best = min(best, (__popc(w ^ cb.w) << 8) | (c + 3));
    }
    int bc = best & 255;
    if (write_cl) cl[(size_t)nh * cL + l] = bc;
    // wave-aggregated histogram into LDS (integer atomics: deterministic)
    for (int c = 0; c < cC; ++c) {
        unsigned long long m = __ballot(bc == c);
        if (m) {
            if (lane < cB) {
                int contrib = __popcll(m & mymb);
                if (contrib) atomicAdd(&hist[c * 32 + lane], contrib);
            }
            if (lane == 63) atomicAdd(&hist[4096 + c], __popcll(m));
        }
    }
    __syncthreads();
    int* dst = partial + (size_t)(nh * TILES + tile) * HW;
    for (int i = tid; i < HW; i += 256) dst[i] = hist[i];
}

// ---------------- Kernel 2c: centroid update / final counts+moff ---------
// grid = 16 blocks x 128 threads (thread = cluster)
__global__ __launch_bounds__(128)
void k_update(const int* __restrict__ partial, unsigned int* __restrict__ cent,
              int* __restrict__ counts, int* __restrict__ moff, int mode)
{
    __shared__ int scn[cC];
    int c = threadIdx.x, nh = blockIdx.x;
    int cnt = 0;
    int bs[cB];
#pragma unroll
    for (int b = 0; b < cB; ++b) bs[b] = 0;
    for (int t = 0; t < TILES; ++t) {
        const int* p = partial + (size_t)(nh * TILES + t) * HW;
        cnt += p[4096 + c];
#pragma unroll
        for (int b = 0; b < cB; ++b) bs[b] += p[c * 32 + b];
    }
    if (mode == 0) {
        if (cnt > 0) {                       // keep old centroid if empty
            unsigned int nw = 0;
#pragma unroll
            for (int b = 0; b < cB; ++b)
                if (2 * bs[b] > cnt) nw |= (1u << b);
            cent[nh * cC + c] = nw;
        }
    } else {
        counts[nh * cC + c] = cnt;
        scn[c] = cnt;
        __syncthreads();
        if (c == 0) {
            int run = 0;
            for (int i = 0; i < cC; ++i) { int v = scn[i]; scn[i] = run; run += v; }
        }
        __syncthreads();
        moff[nh * cC + c] = scn[c];          // exclusive cluster prefix
    }
}

// ---------------- Kernel 2d: parallel stable counting-sort ranks ---------
// grid = 16 nh x 8 tiles = 128 blocks, 256 threads (1 point each)
// pos = moff[nh][c] + sum_{t'<tile} partial[t'].count[c] + in-tile stable rank
__global__ __launch_bounds__(256)
void k_rank(const int* __restrict__ cl, const int* __restrict__ partial,
            const int* __restrict__ moff, int* __restrict__ mlist)
{
    __shared__ int pre[cC];
    __shared__ int wcnt[4][cC];
    int tid = threadIdx.x, lane = tid & 63, wid = tid >> 6;
    int tile = blockIdx.x & (TILES - 1), nh = blockIdx.x / TILES;
    if (tid < cC) {
        int s = 0;
        for (int t = 0; t < tile; ++t)
            s += partial[(size_t)(nh * TILES + t) * HW + 4096 + tid];
        pre[tid] = s + moff[nh * cC + tid];
    }
    int l = tile * 256 + tid;
    int bc = cl[(size_t)nh * cL + l];
    unsigned long long ltmask = (1ull << lane) - 1ull;   // lanes below me
    int myrank = 0;
    for (int c = 0; c < cC; ++c) {
        unsigned long long m = __ballot(bc == c);
        if (lane == 0) wcnt[wid][c] = __popcll(m);
        if (bc == c) myrank = __popcll(m & ltmask);
    }
    __syncthreads();
    int off = pre[bc] + myrank;
    for (int w = 0; w < 4; ++w)
        if (w < wid) off += wcnt[w][bc];
    mlist[(size_t)nh * cL + off] = l;
}

// ---------------- Kernel 3: cluster-mean queries Qg ----------------------
// one block (64 lanes = e) per (nh,c); dense member list, batched loads,
// strict ascending-l single-accumulator chain (bit-exact vs np GEMM)
__global__ __launch_bounds__(64)
void k_qg(const float* __restrict__ q, const int* __restrict__ mlist,
          const int* __restrict__ moff, const int* __restrict__ counts,
          float* __restrict__ Qg)
{
    int b = blockIdx.x;                 // nh*cC + c
    int nh = b >> 7;
    int h = nh % cH, n = nh / cH;
    int lane = threadIdx.x;
    int off = moff[b];
    int cnt = counts[b];
    const int* ml = mlist + (size_t)nh * cL + off;
    const float* qb = q + ((size_t)n * cL * cH + h) * cE + lane;
    float acc = 0.f;
    int j = 0;
    for (; j + 4 <= cnt; j += 4) {
        int i0 = ml[j], i1 = ml[j + 1], i2 = ml[j + 2], i3 = ml[j + 3];
        float v0 = qb[(size_t)i0 * cH * cE];
        float v1 = qb[(size_t)i1 * cH * cE];
        float v2 = qb[(size_t)i2 * cH * cE];
        float v3 = qb[(size_t)i3 * cH * cE];
        acc += v0; acc += v1; acc += v2; acc += v3;    // in-order chain
    }
    for (; j < cnt; ++j) acc += qb[(size_t)ml[j] * cH * cE];
    float cs = (float)(cnt > 0 ? cnt : 1);
    Qg[(size_t)b * cE + lane] = acc / cs;
}

// ---------------- Kernel 4a: QK = Qg . k^T  (tiled GEMM, exact chains) ---
// grid = nh(16) x s-tiles(16 of 128); block 256 = 16 ty (c) x 16 tx (s)
__global__ __launch_bounds__(256)
void k_qk_gemm(const float* __restrict__ key, const float* __restrict__ Qg,
               float* __restrict__ QK)
{
    __shared__ float qgT[cE][cC + 2];      // [e][c]
    __shared__ float kT[cE][128 + 2];      // [e][s_local]
    int tid = threadIdx.x;
    int bs = blockIdx.x & 15;              // s-tile
    int nh = blockIdx.x >> 4;
    int h = nh % cH, n = nh / cH;
    const float4* qsrc = (const float4*)(Qg + (size_t)nh * cC * cE);
#pragma unroll
    for (int i = 0; i < 8; ++i) {
        int f = tid + 256 * i;
        int c = f >> 4, e4 = (f & 15) << 2;
        float4 v = qsrc[f];
        qgT[e4+0][c] = v.x; qgT[e4+1][c] = v.y; qgT[e4+2][c] = v.z; qgT[e4+3][c] = v.w;
    }
    const float* kb = key + (size_t)n * cS * cH * cE + (size_t)h * cE;
    int s0 = bs * 128;
#pragma unroll
    for (int i = 0; i < 8; ++i) {
        int f = tid + 256 * i;
        int s = f >> 4, e4 = (f & 15) << 2;
        float4 v = *(const float4*)(kb + (size_t)(s0 + s) * (cH * cE) + e4);
        kT[e4+0][s] = v.x; kT[e4+1][s] = v.y; kT[e4+2][s] = v.z; kT[e4+3][s] = v.w;
    }
    __syncthreads();
    int tx = tid & 15, ty = tid >> 4;
    float acc[8][8];
#pragma unroll
    for (int i = 0; i < 8; ++i)
#pragma unroll
        for (int j = 0; j < 8; ++j) acc[i][j] = 0.f;
    for (int e = 0; e < cE; ++e) {
        float qv[8], kv[8];
#pragma unroll
        for (int i = 0; i < 8; ++i) qv[i] = qgT[e][ty + 16 * i];
#pragma unroll
        for (int j = 0; j < 8; ++j) kv[j] = kT[e][tx + 16 * j];
#pragma unroll
        for (int i = 0; i < 8; ++i)
#pragma unroll
            for (int j = 0; j < 8; ++j)
                acc[i][j] = fmaf(qv[i], kv[j], acc[i][j]);   // ascending-e chain
    }
    float* dst = QK + (size_t)nh * cC * cS + s0;
#pragma unroll
    for (int i = 0; i < 8; ++i)
#pragma unroll
        for (int j = 0; j < 8; ++j)
            dst[(size_t)(ty + 16 * i) * cS + tx + 16 * j] = acc[i][j];
}

// ---------------- Kernel 4b: radix-select top-32 + softmax -> P ----------
// one block (256 threads) per (n,h,c) row; row register-resident (8/thread).
// Selection is integer-exact on monotone keys -> topk indices bit-identical
// to the iterative (value desc, index asc) semantics.
__global__ __launch_bounds__(256)
void k_sel(float* __restrict__ QK, int* __restrict__ topk,
           float* __restrict__ abk)
{
    __shared__ int sbins[4 * 257];        // 4 wave copies, bank-staggered
    __shared__ int ired[4];
    __shared__ float fred[4];
    __shared__ unsigned skey[cK];
    __shared__ float sval[cK];
    __shared__ int sidx[cK];
    __shared__ int stopk[cK];
    __shared__ int sDig, sRem, scnt;
    __shared__ float sM;
    int tid = threadIdx.x, lane = tid & 63, wid = tid >> 6;
    int b = blockIdx.x;                  // (n*H + h)*C + c
    float* qrow = QK + (size_t)b * cS;
    float v[8]; unsigned key[8];
#pragma unroll
    for (int j = 0; j < 8; ++j) {
        float f = qrow[tid + j * 256];
        v[j] = f;
        unsigned u = __float_as_uint(f);
        key[j] = (u & 0x80000000u) ? ~u : (u | 0x80000000u);   // monotone map
    }
    if (tid == 0) { sRem = cK; scnt = 0; }
    unsigned pfx = 0;
    // 4x8-bit radix select for the 32nd-largest key
    for (int pass = 0; pass < 4; ++pass) {
        int sh = 24 - 8 * pass;
        for (int i = tid; i < 4 * 257; i += 256) sbins[i] = 0;
        __syncthreads();
        int rem = sRem;
#pragma unroll
        for (int j = 0; j < 8; ++j) {
            bool cand = (pass == 0) || ((key[j] >> (sh + 8)) == pfx);
            if (cand) atomicAdd(&sbins[wid * 257 + ((key[j] >> sh) & 255)], 1);
        }
        __syncthreads();
        if (wid == 0) {
            int d0 = lane * 4;
            int c0 = sbins[d0] + sbins[257 + d0] + sbins[514 + d0] + sbins[771 + d0];
            int c1 = sbins[d0+1] + sbins[257+d0+1] + sbins[514+d0+1] + sbins[771+d0+1];
            int c2 = sbins[d0+2] + sbins[257+d0+2] + sbins[514+d0+2] + sbins[771+d0+2];
            int c3 = sbins[d0+3] + sbins[257+d0+3] + sbins[514+d0+3] + sbins[771+d0+3];
            int tot = c0 + c1 + c2 + c3;
            int incl = tot;                           // backward inclusive scan
#pragma unroll
            for (int off = 1; off < 64; off <<= 1) {
                int o = __shfl_down(incl, off);
                if (lane + off < 64) incl += o;
            }
            int sufHi = incl - tot;                   // count with digit > my range
            int G3 = sufHi, G2 = sufHi + c3, G1 = G2 + c2, G0 = G1 + c1;
            int hit = -1, hG = 0;
            if (G0 < rem && rem <= G0 + c0) { hit = d0 + 0; hG = G0; }
            if (G1 < rem && rem <= G1 + c1) { hit = d0 + 1; hG = G1; }
            if (G2 < rem && rem <= G2 + c2) { hit = d0 + 2; hG = G2; }
            if (G3 < rem && rem <= G3 + c3) { hit = d0 + 3; hG = G3; }
            unsigned long long m = __ballot(hit >= 0);
            int src = __ffsll((long long)m) - 1;
            int dsel = __shfl(hit, src);
            int Gsel = __shfl(hG, src);
            if (lane == 0) { sDig = dsel; sRem = rem - Gsel; }
        }
        __syncthreads();
        pfx = (pfx << 8) | (unsigned)sDig;
    }
    unsigned T = pfx;
    int need = sRem;                      // ties at T to take (smallest indices)
    // count ties
    int myT = 0;
#pragma unroll
    for (int j = 0; j < 8; ++j) myT += (key[j] == T);
#pragma unroll
    for (int off = 1; off < 64; off <<= 1) myT += __shfl_xor(myT, off);
    if (lane == 0) ired[wid] = myT;
    __syncthreads();
    int tieTot = ((ired[0] + ired[1]) + ired[2]) + ired[3];
    int tieCut = 0x7fffffff;
    if (tieTot != need) {                 // rare: pick need-th smallest tie index
        int last = -1;
        for (int t = 0; t < need; ++t) {
            int mymin = 0x7fffffff;
#pragma unroll
            for (int j = 0; j < 8; ++j) {
                int idx = tid + j * 256;
                if (key[j] == T && idx > last) mymin = min(mymin, idx);
            }
#pragma unroll
            for (int off = 1; off < 64; off <<= 1)
                mymin = min(mymin, __shfl_xor(mymin, off));
            __syncthreads();              // protect ired reuse
            if (lane == 0) ired[wid] = mymin;
            __syncthreads();
            last = min(min(ired[0], ired[1]), min(ired[2], ired[3]));
        }
        tieCut = last;
    }
    // gather selected (exactly 32) into LDS; order arbitrary, rank fixes it
    __syncthreads();
    int selm = 0;
#pragma unroll
    for (int j = 0; j < 8; ++j) {
        int idx = tid + j * 256;
        bool s_ = (key[j] > T) || (key[j] == T && idx <= tieCut);
        if (s_) {
            int slot = atomicAdd(&scnt, 1);
            skey[slot] = key[j]; sidx[slot] = idx; sval[slot] = v[j];
            selm |= (1 << j);
        }
    }
    __syncthreads();
    // rank the 32 by (value desc, index asc); deterministic
    if (tid < cK) {
        unsigned kt = skey[tid]; int it = sidx[tid];
        int rank = 0;
#pragma unroll
        for (int j = 0; j < cK; ++j)
            rank += (skey[j] > kt) || (skey[j] == kt && sidx[j] < it);
        stopk[rank] = it;
        if (rank == 0) sM = sval[tid];    // row max (exact)
    }
    __syncthreads();
    if (tid < cK) topk[(size_t)b * cK + tid] = stopk[tid];
    // softmax (float outputs only; loose tolerance)
    float M = sM;
    float e8[8]; float ps = 0.f;
#pragma unroll
    for (int j = 0; j < 8; ++j) { e8[j] = expf(0.125f * (v[j] - M)); ps += e8[j]; }
#pragma unroll
    for (int off = 1; off < 64; off <<= 1) ps += __shfl_xor(ps, off);
    if (lane == 0) fred[wid] = ps;
    __syncthreads();
    float den = ((fred[0] + fred[1]) + fred[2]) + fred[3];
    float ab = 0.f;
#pragma unroll
    for (int j = 0; j < 8; ++j) {
        float P = (selm & (1 << j)) ? 0.f : e8[j] / den;
        ab += P;
        qrow[tid + j * 256] = P;
    }
#pragma unroll
    for (int off = 1; off < 64; off <<= 1) ab += __shfl_xor(ab, off);
    __syncthreads();                      // protect fred reuse
    if (lane == 0) fred[wid] = ab;
    __syncthreads();
    if (tid == 0) abk[b] = ((fred[0] + fred[1]) + fred[2]) + fred[3];
}

// ---------------- Kernel 4c: Vb_g partials = P . v (split-K GEMM) --------
// grid = nh(16) x sk(8) x ch(2);  block 256 = 16 ty (c) x 16 tx (d4)
__global__ __launch_bounds__(256)
void k_pv(const float* __restrict__ P, const float* __restrict__ val,
          float* __restrict__ part)
{
    __shared__ float pT[64][64 + 2];       // [c_local][s_sub]
    __shared__ float vT[64][cD + 4];       // [s_sub][d]
    int tid = threadIdx.x;
    int ch = blockIdx.x & 1;
    int sk = (blockIdx.x >> 1) & 7;
    int nh = blockIdx.x >> 4;
    int h = nh % cH, n = nh / cH;
    int tx = tid & 15, ty = tid >> 4;
    float acc[4][4];
#pragma unroll
    for (int i = 0; i < 4; ++i)
#pragma unroll
        for (int j = 0; j < 4; ++j) acc[i][j] = 0.f;
    const float* pb = P + ((size_t)nh * cC + ch * 64) * cS;
    const float* vb = val + (size_t)n * cS * cH * cD + (size_t)h * cD;
    for (int sub = 0; sub < CHUNK / 64; ++sub) {
        int s0 = sk * CHUNK + sub * 64;
#pragma unroll
        for (int i = 0; i < 4; ++i) {
            int f = tid + 256 * i;
            int c = f >> 4, s4 = (f & 15) << 2;
            float4 v = *(const float4*)(pb + (size_t)c * cS + s0 + s4);
            pT[c][s4+0] = v.x; pT[c][s4+1] = v.y; pT[c][s4+2] = v.z; pT[c][s4+3] = v.w;
        }
#pragma unroll
        for (int i = 0; i < 4; ++i) {
            int f = tid + 256 * i;
            int ss = f >> 4, d4 = (f & 15) << 2;
            float4 v = *(const float4*)(vb + (size_t)(s0 + ss) * (cH * cD) + d4);
            vT[ss][d4+0] = v.x; vT[ss][d4+1] = v.y; vT[ss][d4+2] = v.z; vT[ss][d4+3] = v.w;
        }
        __syncthreads();
        for (int ss = 0; ss < 64; ++ss) {
            float pv[4];
#pragma unroll
            for (int i = 0; i < 4; ++i) pv[i] = pT[ty + 16 * i][ss];
            float4 vv = *(const float4*)&vT[ss][tx * 4];
#pragma unroll
            for (int i = 0; i < 4; ++i) {
                acc[i][0] = fmaf(pv[i], vv.x, acc[i][0]);
                acc[i][1] = fmaf(pv[i], vv.y, acc[i][1]);
                acc[i][2] = fmaf(pv[i], vv.z, acc[i][2]);
                acc[i][3] = fmaf(pv[i], vv.w, acc[i][3]);
            }
        }
        __syncthreads();
    }
    float* dst = part + (((size_t)sk * cNH + nh) * cC + ch * 64) * cD;
#pragma unroll
    for (int i = 0; i < 4; ++i) {
        float4 o; o.x = acc[i][0]; o.y = acc[i][1]; o.z = acc[i][2]; o.w = acc[i][3];
        *(float4*)(dst + (size_t)(ty + 16 * i) * cD + tx * 4) = o;
    }
}

// ---------------- Kernel 4d: reduce split-K partials ---------------------
__global__ __launch_bounds__(256)
void k_red(const float* __restrict__ part, float* __restrict__ vbg)
{
    int i = blockIdx.x * 256 + threadIdx.x;      // over 16*128*64 = 131072
    float acc = 0.f;
    for (int sk = 0; sk < SK; ++sk) acc += part[(size_t)sk * (cNH * cC * cD) + i];
    vbg[i] = acc;
}

// ---------------- Kernel 5: per-cluster epilogue (K in registers) --------
// one block per (nh,c); V staged in LDS once; lane pair k holds K[t_k] half
// in 8 float4 registers -> QK is pure-register fmaf, no LDS conflicts.
// All FP chains keep the validated operand order -> bit-identical outputs.
__global__ __launch_bounds__(256)
void k_out(const float* __restrict__ q, const float* __restrict__ key,
           const float* __restrict__ val, const int* __restrict__ mlist,
           const int* __restrict__ moff, const int* __restrict__ counts,
           const float* __restrict__ abk, const float* __restrict__ vbg,
           const int* __restrict__ topk, float* __restrict__ out)
{
    __shared__ float vlds[cK][cD + 1];   // [k][d]: 2-way alias (free)
    __shared__ float aslds[4][cK];
    __shared__ int   st[cK];
    int tid = threadIdx.x, lane = tid & 63, wid = tid >> 6;
    int b = blockIdx.x;                 // nh*cC + c
    int nh = b >> 7;
    int h = nh % cH, n = nh / cH;
    if (tid < cK) st[tid] = topk[(size_t)b * cK + tid];
    __syncthreads();
    const float* kb = key + ((size_t)n * cS * cH + h) * cE;
    const float* vb = val + ((size_t)n * cS * cH + h) * cD;
    for (int r = wid; r < cK; r += 4)
        vlds[r][lane] = vb[(size_t)st[r] * cH * cD + lane];
    int k = lane >> 1, hh = lane & 1;
    // my K half-row into registers (ascending e within half)
    float4 kreg[8];
    {
        const float* kr = kb + (size_t)st[k] * cH * cE + hh * 32;
#pragma unroll
        for (int j = 0; j < 8; ++j) kreg[j] = ((const float4*)kr)[j];
    }
    __syncthreads();
    int cnt = counts[b];
    int off = moff[b];
    float scale = 1.0f - abk[b];
    float vbgd = vbg[(size_t)b * cD + lane];
    float stf = (lane < cK) ? (float)st[lane] : 0.f;
    const int* ml = mlist + (size_t)nh * cL + off;
    const size_t off1 = (size_t)cN * cL * cH * cD;
    const size_t off2 = off1 + (size_t)cN * cH * cL * cK;
    for (int m = wid; m < cnt; m += 4) {             // wave-uniform loop
        int l = ml[m];
        const float* qrow = q + (((size_t)n * cL + l) * cH + h) * cE + hh * 32;
        float4 qf[8];
#pragma unroll
        for (int j = 0; j < 8; ++j) qf[j] = ((const float4*)qrow)[j];
        // half-dot: ascending e within my half, register operands only
        float partial = 0.f;
#pragma unroll
        for (int j = 0; j < 8; ++j) {
            partial = fmaf(qf[j].x, kreg[j].x, partial);
            partial = fmaf(qf[j].y, kreg[j].y, partial);
            partial = fmaf(qf[j].z, kreg[j].z, partial);
            partial = fmaf(qf[j].w, kreg[j].w, partial);
        }
        float qk = partial + __shfl_xor(partial, 1);   // low half + high half
        float M = qk;
#pragma unroll
        for (int o = 2; o < 64; o <<= 1) M = fmaxf(M, __shfl_xor(M, o));
        float ev = expf(0.125f * (qk - M));
        float den = ev;
#pragma unroll
        for (int o = 2; o < 64; o <<= 1) den += __shfl_xor(den, o);
        float as_ = (ev / den) * scale;                // A_s for my k
        if (!hh) aslds[wid][k] = as_;
        // PV: lane = d; aslds broadcast, vlds 2-way
        float acc = 0.f;
#pragma unroll
        for (int j = 0; j < cK; ++j)
            acc = fmaf(aslds[wid][j], vlds[j][lane], acc);
        acc += vbgd;
        int qidx = nh * cL + l;
        out[(((size_t)n * cL + l) * cH + h) * cD + lane] = acc;   // (N,L,H,D)
        if (lane < cK) {
            out[off1 + (size_t)qidx * cK + lane] = stf;           // sparse_index
            out[off2 + (size_t)qidx * cK + lane] = aslds[wid][lane]; // A_topk
        }
    }
}

// ---------------- launch -------------------------------------------------
extern "C" void kernel_launch(void* const* d_in, const int* in_sizes, int n_in,
                              void* d_out, int out_size, void* d_ws, size_t ws_size,
                              hipStream_t stream)
{
    (void)in_sizes; (void)n_in; (void)out_size; (void)ws_size;
    const float* q      = (const float*)d_in[0];
    const float* key    = (const float*)d_in[1];
    const float* val    = (const float*)d_in[2];
    const float* planes = (const float*)d_in[3];
    char* w = (char*)d_ws;
    unsigned int* bits = (unsigned int*)w;  w += (size_t)cN * cH * cL * 4;
    int*   cl     = (int*)w;                w += (size_t)cN * cH * cL * 4;
    int*   counts = (int*)w;                w += (size_t)cN * cH * cC * 4;
    float* abk    = (float*)w;              w += (size_t)cN * cH * cC * 4;
    float* Qg     = (float*)w;              w += (size_t)cN * cH * cC * cE * 4;
    float* vbg    = (float*)w;              w += (size_t)cN * cH * cC * cD * 4;
    int*   topkp  = (int*)w;                w += (size_t)cN * cH * cC * cK * 4;
    float* QK     = (float*)w;              w += (size_t)cNH * cC * cS * 4;      // 16 MB (QK -> P in place)
    float* part   = (float*)w;              w += (size_t)SK * cNH * cC * cD * 4; // 4 MB
    unsigned int* cent = (unsigned int*)w;  w += (size_t)cNH * cC * 4;           // 8 KB
    int*   partial = (int*)w;               w += (size_t)cNH * TILES * HW * 4;   // 2.2 MB
    int*   mlist  = (int*)w;                w += (size_t)cNH * cL * 4;           // 128 KB
    int*   moff   = (int*)w;                w += (size_t)cNH * cC * 4;           // 8 KB
    float* out = (float*)d_out;

    k_bits   <<<(cN * cH * cL) / 256, 256, 0, stream>>>(q, planes, bits);
    k_init   <<<(cNH * cC) / 256, 256, 0, stream>>>(bits, cent);
    for (int it = 0; it < cIT; ++it) {
        k_assign <<<cNH * TILES, 256, 0, stream>>>(bits, cent, partial, cl, 0);
        k_update <<<cNH, 128, 0, stream>>>(partial, cent, counts, moff, 0);
    }
    k_assign <<<cNH * TILES, 256, 0, stream>>>(bits, cent, partial, cl, 1);
    k_update <<<cNH, 128, 0, stream>>>(partial, cent, counts, moff, 1);
    k_rank   <<<cNH * TILES, 256, 0, stream>>>(cl, partial, moff, mlist);
    k_qg     <<<cNH * cC, 64, 0, stream>>>(q, mlist, moff, counts, Qg);
    k_qk_gemm<<<cNH * 16, 256, 0, stream>>>(key, Qg, QK);
    k_sel    <<<cNH * cC, 256, 0, stream>>>(QK, topkp, abk);
    k_pv     <<<cNH * SK * 2, 256, 0, stream>>>(QK, val, part);
    k_red    <<<(cNH * cC * cD) / 256, 256, 0, stream>>>(part, vbg);
    k_out    <<<cNH * cC, 256, 0, stream>>>(q, key, val, mlist, moff, counts,
                                            abk, vbg, topkp, out);
}

// Round 12
// 352.719 us; speedup vs baseline: 1.2833x; 1.0587x over previous
//
#include <hip/hip_runtime.h>
#include <math.h>

constexpr int cN = 2, cH = 8, cL = 2048, cS = 2048, cE = 64, cD = 64;
constexpr int cC = 128, cK = 32, cB = 32, cIT = 10;
constexpr int cNH = cN * cH;          // 16
constexpr int SK = 8;                 // split-K factor for PV
constexpr int CHUNK = cS / SK;        // 256 s per split
constexpr int TILES = 8;              // point tiles per nh in k_assign
constexpr int HW = cC * 33;           // partial hist words: sbs[128][32] + scnt[128]
constexpr int OSPLIT = 2;             // blocks per cluster in k_out
// TEMP = 1/sqrt(64) = 0.125 exactly

// ---------------- Kernel 1: LSH bits (float4 LDS plane reads) ------------
__global__ __launch_bounds__(256)
void k_bits(const float* __restrict__ q, const float* __restrict__ planes,
            unsigned int* __restrict__ bits)
{
    __shared__ float pl[cB * 68];               // padded rows: 68*4B = 16B-aligned
    int tid = threadIdx.x;
    for (int i = tid; i < cB * (cE + 1); i += 256) {
        int b = i / 65, e = i % 65;
        pl[b * 68 + e] = planes[i];
    }
    __syncthreads();
    int idx = blockIdx.x * 256 + tid;           // (n*H + h)*L + l
    int l = idx % cL, h = (idx / cL) % cH, n = idx / (cL * cH);
    const float* qr = q + (((size_t)n * cL + l) * cH + h) * cE;
    float qv[cE];
#pragma unroll
    for (int e4 = 0; e4 < cE / 4; ++e4) {
        float4 f = ((const float4*)qr)[e4];
        qv[4*e4+0] = f.x; qv[4*e4+1] = f.y; qv[4*e4+2] = f.z; qv[4*e4+3] = f.w;
    }
    unsigned int w = 0;
    for (int b = 0; b < cB; ++b) {
        const float4* pr = (const float4*)(pl + b * 68);
        float acc = 0.f;
#pragma unroll
        for (int e4 = 0; e4 < cE / 4; ++e4) {
            float4 f = pr[e4];
            acc = fmaf(qv[4*e4+0], f.x, acc);
            acc = fmaf(qv[4*e4+1], f.y, acc);
            acc = fmaf(qv[4*e4+2], f.z, acc);
            acc = fmaf(qv[4*e4+3], f.w, acc);
        }
        acc += pl[b * 68 + 64];
        if (acc > 0.f) w |= (1u << b);
    }
    bits[idx] = w;
}

// ---------------- Kernel 2a: initial centroids ---------------------------
__global__ __launch_bounds__(256)
void k_init(const unsigned int* __restrict__ bits, unsigned int* __restrict__ cent)
{
    int i = blockIdx.x * 256 + threadIdx.x;     // nh*128 + c
    int c = i & 127, nh = i >> 7;
    // idx0 = linspace(0, L-1, C).astype(int32): floor(c*2047/127), endpoint exact
    int i0 = (int)(((double)c * 2047.0) / 127.0);
    cent[i] = bits[(size_t)nh * cL + i0];
}

// ---------------- Kernel 2b: assignment + partial histograms -------------
// grid = 16 nh x 8 tiles = 128 blocks, 256 threads (1 point each)
__global__ __launch_bounds__(256)
void k_assign(const unsigned int* __restrict__ bits,
              const unsigned int* __restrict__ cent,
              int* __restrict__ partial, int* __restrict__ cl, int write_cl)
{
    __shared__ unsigned int scb[cC] __attribute__((aligned(16)));
    __shared__ int hist[HW];      // [c*32+b] bitsums, [4096+c] counts
    int tid = threadIdx.x;
    int lane = tid & 63;
    int tile = blockIdx.x & (TILES - 1), nh = blockIdx.x / TILES;
    if (tid < cC) scb[tid] = cent[nh * cC + tid];
    for (int i = tid; i < HW; i += 256) hist[i] = 0;
    int l = tile * 256 + tid;
    unsigned int w = bits[(size_t)nh * cL + l];
    // per-lane bit ballots over this wave's 64 points (lane b&31 keeps bit b)
    unsigned long long mymb = 0ull;
#pragma unroll
    for (int b = 0; b < cB; ++b) {
        unsigned long long m = __ballot((w >> b) & 1u);
        if ((lane & 31) == b) mymb = m;
    }
    __syncthreads();
    const uint4* scb4 = (const uint4*)scb;
    // packed key = (hamming<<8)|c -> min = lowest dist, tie lowest c
    int best = 0x7fffffff;
    for (int c4 = 0; c4 < cC / 4; ++c4) {
        uint4 cb = scb4[c4];
        int c = c4 * 4;
        best = min(best, (__popc(w ^ cb.x) << 8) | c);
        best = min(best, (__popc(w ^ cb.y) << 8) | (c + 1));
        best = min(best, (__popc(w ^ cb.z) << 8) | (c + 2));
        best = min(best, (__popc(w ^ cb.w) << 8) | (c + 3));
    }
    int bc = best & 255;
    if (write_cl) cl[(size_t)nh * cL + l] = bc;
    // wave-aggregated histogram into LDS (integer atomics: deterministic)
    for (int c = 0; c < cC; ++c) {
        unsigned long long m = __ballot(bc == c);
        if (m) {
            if (lane < cB) {
                int contrib = __popcll(m & mymb);
                if (contrib) atomicAdd(&hist[c * 32 + lane], contrib);
            }
            if (lane == 63) atomicAdd(&hist[4096 + c], __popcll(m));
        }
    }
    __syncthreads();
    int* dst = partial + (size_t)(nh * TILES + tile) * HW;
    for (int i = tid; i < HW; i += 256) dst[i] = hist[i];
}

// ---------------- Kernel 2c: centroid update / final counts+moff ---------
// grid = 16 blocks x 256 threads; cooperative int4 tile-sum into LDS
__global__ __launch_bounds__(256)
void k_update(const int* __restrict__ partial, unsigned int* __restrict__ cent,
              int* __restrict__ counts, int* __restrict__ moff, int mode)
{
    __shared__ int hsum[HW];
    int tid = threadIdx.x, nh = blockIdx.x;
    const int4* base = (const int4*)(partial + (size_t)nh * TILES * HW);
    for (int i4 = tid; i4 < HW / 4; i4 += 256) {
        int4 s; s.x = 0; s.y = 0; s.z = 0; s.w = 0;
#pragma unroll
        for (int t = 0; t < TILES; ++t) {
            int4 v = base[(size_t)t * (HW / 4) + i4];
            s.x += v.x; s.y += v.y; s.z += v.z; s.w += v.w;
        }
        ((int4*)hsum)[i4] = s;
    }
    __syncthreads();
    int c = tid;
    if (c < cC) {
        int cnt = hsum[4096 + c];
        if (mode == 0) {
            if (cnt > 0) {                       // keep old centroid if empty
                unsigned int nw = 0;
#pragma unroll
                for (int b = 0; b < cB; ++b)
                    if (2 * hsum[c * 32 + b] > cnt) nw |= (1u << b);
                cent[nh * cC + c] = nw;
            }
        } else {
            counts[nh * cC + c] = cnt;
        }
    }
    if (mode == 1 && tid == 0) {
        int run = 0;
        for (int i = 0; i < cC; ++i) { moff[nh * cC + i] = run; run += hsum[4096 + i]; }
    }
}

// ---------------- Kernel 2d: parallel stable counting-sort ranks ---------
// grid = 16 nh x 8 tiles = 128 blocks, 256 threads (1 point each)
// pos = moff[nh][c] + sum_{t'<tile} partial[t'].count[c] + in-tile stable rank
__global__ __launch_bounds__(256)
void k_rank(const int* __restrict__ cl, const int* __restrict__ partial,
            const int* __restrict__ moff, int* __restrict__ mlist)
{
    __shared__ int pre[cC];
    __shared__ int wcnt[4][cC];
    int tid = threadIdx.x, lane = tid & 63, wid = tid >> 6;
    int tile = blockIdx.x & (TILES - 1), nh = blockIdx.x / TILES;
    if (tid < cC) {
        int s = 0;
        for (int t = 0; t < tile; ++t)
            s += partial[(size_t)(nh * TILES + t) * HW + 4096 + tid];
        pre[tid] = s + moff[nh * cC + tid];
    }
    int l = tile * 256 + tid;
    int bc = cl[(size_t)nh * cL + l];
    unsigned long long ltmask = (1ull << lane) - 1ull;   // lanes below me
    int myrank = 0;
    for (int c = 0; c < cC; ++c) {
        unsigned long long m = __ballot(bc == c);
        if (lane == 0) wcnt[wid][c] = __popcll(m);
        if (bc == c) myrank = __popcll(m & ltmask);
    }
    __syncthreads();
    int off = pre[bc] + myrank;
    for (int w = 0; w < 4; ++w)
        if (w < wid) off += wcnt[w][bc];
    mlist[(size_t)nh * cL + off] = l;
}

// ---------------- Kernel 3: cluster-mean queries Qg ----------------------
// one block (64 lanes = e) per (nh,c); dense member list, batched loads,
// strict ascending-l single-accumulator chain (bit-exact vs np GEMM)
__global__ __launch_bounds__(64)
void k_qg(const float* __restrict__ q, const int* __restrict__ mlist,
          const int* __restrict__ moff, const int* __restrict__ counts,
          float* __restrict__ Qg)
{
    int b = blockIdx.x;                 // nh*cC + c
    int nh = b >> 7;
    int h = nh % cH, n = nh / cH;
    int lane = threadIdx.x;
    int off = moff[b];
    int cnt = counts[b];
    const int* ml = mlist + (size_t)nh * cL + off;
    const float* qb = q + ((size_t)n * cL * cH + h) * cE + lane;
    float acc = 0.f;
    int j = 0;
    for (; j + 4 <= cnt; j += 4) {
        int i0 = ml[j], i1 = ml[j + 1], i2 = ml[j + 2], i3 = ml[j + 3];
        float v0 = qb[(size_t)i0 * cH * cE];
        float v1 = qb[(size_t)i1 * cH * cE];
        float v2 = qb[(size_t)i2 * cH * cE];
        float v3 = qb[(size_t)i3 * cH * cE];
        acc += v0; acc += v1; acc += v2; acc += v3;    // in-order chain
    }
    for (; j < cnt; ++j) acc += qb[(size_t)ml[j] * cH * cE];
    float cs = (float)(cnt > 0 ? cnt : 1);
    Qg[(size_t)b * cE + lane] = acc / cs;
}

// ---------------- Kernel 4a: QK = Qg . k^T  (tiled GEMM, exact chains) ---
// grid = nh(16) x s-tiles(16 of 128); block 256 = 16 ty (c) x 16 tx (s)
__global__ __launch_bounds__(256)
void k_qk_gemm(const float* __restrict__ key, const float* __restrict__ Qg,
               float* __restrict__ QK)
{
    __shared__ float qgT[cE][cC + 2];      // [e][c]
    __shared__ float kT[cE][128 + 2];      // [e][s_local]
    int tid = threadIdx.x;
    int bs = blockIdx.x & 15;              // s-tile
    int nh = blockIdx.x >> 4;
    int h = nh % cH, n = nh / cH;
    const float4* qsrc = (const float4*)(Qg + (size_t)nh * cC * cE);
#pragma unroll
    for (int i = 0; i < 8; ++i) {
        int f = tid + 256 * i;
        int c = f >> 4, e4 = (f & 15) << 2;
        float4 v = qsrc[f];
        qgT[e4+0][c] = v.x; qgT[e4+1][c] = v.y; qgT[e4+2][c] = v.z; qgT[e4+3][c] = v.w;
    }
    const float* kb = key + (size_t)n * cS * cH * cE + (size_t)h * cE;
    int s0 = bs * 128;
#pragma unroll
    for (int i = 0; i < 8; ++i) {
        int f = tid + 256 * i;
        int s = f >> 4, e4 = (f & 15) << 2;
        float4 v = *(const float4*)(kb + (size_t)(s0 + s) * (cH * cE) + e4);
        kT[e4+0][s] = v.x; kT[e4+1][s] = v.y; kT[e4+2][s] = v.z; kT[e4+3][s] = v.w;
    }
    __syncthreads();
    int tx = tid & 15, ty = tid >> 4;
    float acc[8][8];
#pragma unroll
    for (int i = 0; i < 8; ++i)
#pragma unroll
        for (int j = 0; j < 8; ++j) acc[i][j] = 0.f;
    for (int e = 0; e < cE; ++e) {
        float qv[8], kv[8];
#pragma unroll
        for (int i = 0; i < 8; ++i) qv[i] = qgT[e][ty + 16 * i];
#pragma unroll
        for (int j = 0; j < 8; ++j) kv[j] = kT[e][tx + 16 * j];
#pragma unroll
        for (int i = 0; i < 8; ++i)
#pragma unroll
            for (int j = 0; j < 8; ++j)
                acc[i][j] = fmaf(qv[i], kv[j], acc[i][j]);   // ascending-e chain
    }
    float* dst = QK + (size_t)nh * cC * cS + s0;
#pragma unroll
    for (int i = 0; i < 8; ++i)
#pragma unroll
        for (int j = 0; j < 8; ++j)
            dst[(size_t)(ty + 16 * i) * cS + tx + 16 * j] = acc[i][j];
}

// ---------------- Kernel 4b: radix-select top-32 + softmax -> P ----------
// one block (256 threads) per (n,h,c) row; row register-resident (8/thread).
// Selection is integer-exact on monotone keys -> topk indices bit-identical
// to the iterative (value desc, index asc) semantics.
__global__ __launch_bounds__(256)
void k_sel(float* __restrict__ QK, int* __restrict__ topk,
           float* __restrict__ abk)
{
    __shared__ int sbins[4 * 257];        // 4 wave copies, bank-staggered
    __shared__ int ired[4];
    __shared__ float fred[4];
    __shared__ unsigned skey[cK];
    __shared__ float sval[cK];
    __shared__ int sidx[cK];
    __shared__ int stopk[cK];
    __shared__ int sDig, sRem, scnt;
    __shared__ float sM;
    int tid = threadIdx.x, lane = tid & 63, wid = tid >> 6;
    int b = blockIdx.x;                  // (n*H + h)*C + c
    float* qrow = QK + (size_t)b * cS;
    float v[8]; unsigned key[8];
#pragma unroll
    for (int j = 0; j < 8; ++j) {
        float f = qrow[tid + j * 256];
        v[j] = f;
        unsigned u = __float_as_uint(f);
        key[j] = (u & 0x80000000u) ? ~u : (u | 0x80000000u);   // monotone map
    }
    if (tid == 0) { sRem = cK; scnt = 0; }
    unsigned pfx = 0;
    // 4x8-bit radix select for the 32nd-largest key
    for (int pass = 0; pass < 4; ++pass) {
        int sh = 24 - 8 * pass;
        for (int i = tid; i < 4 * 257; i += 256) sbins[i] = 0;
        __syncthreads();
        int rem = sRem;
#pragma unroll
        for (int j = 0; j < 8; ++j) {
            bool cand = (pass == 0) || ((key[j] >> (sh + 8)) == pfx);
            if (cand) atomicAdd(&sbins[wid * 257 + ((key[j] >> sh) & 255)], 1);
        }
        __syncthreads();
        if (wid == 0) {
            int d0 = lane * 4;
            int c0 = sbins[d0] + sbins[257 + d0] + sbins[514 + d0] + sbins[771 + d0];
            int c1 = sbins[d0+1] + sbins[257+d0+1] + sbins[514+d0+1] + sbins[771+d0+1];
            int c2 = sbins[d0+2] + sbins[257+d0+2] + sbins[514+d0+2] + sbins[771+d0+2];
            int c3 = sbins[d0+3] + sbins[257+d0+3] + sbins[514+d0+3] + sbins[771+d0+3];
            int tot = c0 + c1 + c2 + c3;
            int incl = tot;                           // backward inclusive scan
#pragma unroll
            for (int off = 1; off < 64; off <<= 1) {
                int o = __shfl_down(incl, off);
                if (lane + off < 64) incl += o;
            }
            int sufHi = incl - tot;                   // count with digit > my range
            int G3 = sufHi, G2 = sufHi + c3, G1 = G2 + c2, G0 = G1 + c1;
            int hit = -1, hG = 0;
            if (G0 < rem && rem <= G0 + c0) { hit = d0 + 0; hG = G0; }
            if (G1 < rem && rem <= G1 + c1) { hit = d0 + 1; hG = G1; }
            if (G2 < rem && rem <= G2 + c2) { hit = d0 + 2; hG = G2; }
            if (G3 < rem && rem <= G3 + c3) { hit = d0 + 3; hG = G3; }
            unsigned long long m = __ballot(hit >= 0);
            int src = __ffsll((long long)m) - 1;
            int dsel = __shfl(hit, src);
            int Gsel = __shfl(hG, src);
            if (lane == 0) { sDig = dsel; sRem = rem - Gsel; }
        }
        __syncthreads();
        pfx = (pfx << 8) | (unsigned)sDig;
    }
    unsigned T = pfx;
    int need = sRem;                      // ties at T to take (smallest indices)
    // count ties
    int myT = 0;
#pragma unroll
    for (int j = 0; j < 8; ++j) myT += (key[j] == T);
#pragma unroll
    for (int off = 1; off < 64; off <<= 1) myT += __shfl_xor(myT, off);
    if (lane == 0) ired[wid] = myT;
    __syncthreads();
    int tieTot = ((ired[0] + ired[1]) + ired[2]) + ired[3];
    int tieCut = 0x7fffffff;
    if (tieTot != need) {                 // rare: pick need-th smallest tie index
        int last = -1;
        for (int t = 0; t < need; ++t) {
            int mymin = 0x7fffffff;
#pragma unroll
            for (int j = 0; j < 8; ++j) {
                int idx = tid + j * 256;
                if (key[j] == T && idx > last) mymin = min(mymin, idx);
            }
#pragma unroll
            for (int off = 1; off < 64; off <<= 1)
                mymin = min(mymin, __shfl_xor(mymin, off));
            __syncthreads();              // protect ired reuse
            if (lane == 0) ired[wid] = mymin;
            __syncthreads();
            last = min(min(ired[0], ired[1]), min(ired[2], ired[3]));
        }
        tieCut = last;
    }
    // gather selected (exactly 32) into LDS; order arbitrary, rank fixes it
    __syncthreads();
    int selm = 0;
#pragma unroll
    for (int j = 0; j < 8; ++j) {
        int idx = tid + j * 256;
        bool s_ = (key[j] > T) || (key[j] == T && idx <= tieCut);
        if (s_) {
            int slot = atomicAdd(&scnt, 1);
            skey[slot] = key[j]; sidx[slot] = idx; sval[slot] = v[j];
            selm |= (1 << j);
        }
    }
    __syncthreads();
    // rank the 32 by (value desc, index asc); deterministic
    if (tid < cK) {
        unsigned kt = skey[tid]; int it = sidx[tid];
        int rank = 0;
#pragma unroll
        for (int j = 0; j < cK; ++j)
            rank += (skey[j] > kt) || (skey[j] == kt && sidx[j] < it);
        stopk[rank] = it;
        if (rank == 0) sM = sval[tid];    // row max (exact)
    }
    __syncthreads();
    if (tid < cK) topk[(size_t)b * cK + tid] = stopk[tid];
    // softmax (float outputs only; loose tolerance)
    float M = sM;
    float e8[8]; float ps = 0.f;
#pragma unroll
    for (int j = 0; j < 8; ++j) { e8[j] = expf(0.125f * (v[j] - M)); ps += e8[j]; }
#pragma unroll
    for (int off = 1; off < 64; off <<= 1) ps += __shfl_xor(ps, off);
    if (lane == 0) fred[wid] = ps;
    __syncthreads();
    float den = ((fred[0] + fred[1]) + fred[2]) + fred[3];
    float ab = 0.f;
#pragma unroll
    for (int j = 0; j < 8; ++j) {
        float P = (selm & (1 << j)) ? 0.f : e8[j] / den;
        ab += P;
        qrow[tid + j * 256] = P;
    }
#pragma unroll
    for (int off = 1; off < 64; off <<= 1) ab += __shfl_xor(ab, off);
    __syncthreads();                      // protect fred reuse
    if (lane == 0) fred[wid] = ab;
    __syncthreads();
    if (tid == 0) abk[b] = ((fred[0] + fred[1]) + fred[2]) + fred[3];
}

// ---------------- Kernel 4c: Vb_g partials = P . v (split-K GEMM) --------
// grid = nh(16) x sk(8) x ch(2);  block 256 = 16 ty (c) x 16 tx (d4)
__global__ __launch_bounds__(256)
void k_pv(const float* __restrict__ P, const float* __restrict__ val,
          float* __restrict__ part)
{
    __shared__ float pT[64][64 + 2];       // [c_local][s_sub]
    __shared__ float vT[64][cD + 4];       // [s_sub][d]
    int tid = threadIdx.x;
    int ch = blockIdx.x & 1;
    int sk = (blockIdx.x >> 1) & 7;
    int nh = blockIdx.x >> 4;
    int h = nh % cH, n = nh / cH;
    int tx = tid & 15, ty = tid >> 4;
    float acc[4][4];
#pragma unroll
    for (int i = 0; i < 4; ++i)
#pragma unroll
        for (int j = 0; j < 4; ++j) acc[i][j] = 0.f;
    const float* pb = P + ((size_t)nh * cC + ch * 64) * cS;
    const float* vb = val + (size_t)n * cS * cH * cD + (size_t)h * cD;
    for (int sub = 0; sub < CHUNK / 64; ++sub) {
        int s0 = sk * CHUNK + sub * 64;
#pragma unroll
        for (int i = 0; i < 4; ++i) {
            int f = tid + 256 * i;
            int c = f >> 4, s4 = (f & 15) << 2;
            float4 v = *(const float4*)(pb + (size_t)c * cS + s0 + s4);
            pT[c][s4+0] = v.x; pT[c][s4+1] = v.y; pT[c][s4+2] = v.z; pT[c][s4+3] = v.w;
        }
#pragma unroll
        for (int i = 0; i < 4; ++i) {
            int f = tid + 256 * i;
            int ss = f >> 4, d4 = (f & 15) << 2;
            float4 v = *(const float4*)(vb + (size_t)(s0 + ss) * (cH * cD) + d4);
            vT[ss][d4+0] = v.x; vT[ss][d4+1] = v.y; vT[ss][d4+2] = v.z; vT[ss][d4+3] = v.w;
        }
        __syncthreads();
        for (int ss = 0; ss < 64; ++ss) {
            float pv[4];
#pragma unroll
            for (int i = 0; i < 4; ++i) pv[i] = pT[ty + 16 * i][ss];
            float4 vv = *(const float4*)&vT[ss][tx * 4];
#pragma unroll
            for (int i = 0; i < 4; ++i) {
                acc[i][0] = fmaf(pv[i], vv.x, acc[i][0]);
                acc[i][1] = fmaf(pv[i], vv.y, acc[i][1]);
                acc[i][2] = fmaf(pv[i], vv.z, acc[i][2]);
                acc[i][3] = fmaf(pv[i], vv.w, acc[i][3]);
            }
        }
        __syncthreads();
    }
    float* dst = part + (((size_t)sk * cNH + nh) * cC + ch * 64) * cD;
#pragma unroll
    for (int i = 0; i < 4; ++i) {
        float4 o; o.x = acc[i][0]; o.y = acc[i][1]; o.z = acc[i][2]; o.w = acc[i][3];
        *(float4*)(dst + (size_t)(ty + 16 * i) * cD + tx * 4) = o;
    }
}

// ---------------- Kernel 4d: reduce split-K partials ---------------------
__global__ __launch_bounds__(256)
void k_red(const float* __restrict__ part, float* __restrict__ vbg)
{
    int i = blockIdx.x * 256 + threadIdx.x;      // over 16*128*64 = 131072
    float acc = 0.f;
    for (int sk = 0; sk < SK; ++sk) acc += part[(size_t)sk * (cNH * cC * cD) + i];
    vbg[i] = acc;
}

// ---------------- Kernel 5: per-cluster epilogue (K regs, 2-member ILP) --
// grid = cluster x OSPLIT; V in LDS, K half-rows in registers; each wave
// processes TWO members per iteration (independent chains -> 2x ILP,
// shared vlds reads). FP chains operand-identical -> bit-identical output.
__global__ __launch_bounds__(256)
void k_out(const float* __restrict__ q, const float* __restrict__ key,
           const float* __restrict__ val, const int* __restrict__ mlist,
           const int* __restrict__ moff, const int* __restrict__ counts,
           const float* __restrict__ abk, const float* __restrict__ vbg,
           const int* __restrict__ topk, float* __restrict__ out)
{
    __shared__ float vlds[cK][cD + 1];   // [k][d]: 2-way alias (free)
    __shared__ float aslds[4][2][cK];
    __shared__ int   st[cK];
    int tid = threadIdx.x, lane = tid & 63, wid = tid >> 6;
    int bb = blockIdx.x;
    int p = bb & (OSPLIT - 1);
    int b = bb / OSPLIT;                // nh*cC + c
    int nh = b >> 7;
    int h = nh % cH, n = nh / cH;
    if (tid < cK) st[tid] = topk[(size_t)b * cK + tid];
    __syncthreads();
    const float* kb = key + ((size_t)n * cS * cH + h) * cE;
    const float* vb = val + ((size_t)n * cS * cH + h) * cD;
    for (int r = wid; r < cK; r += 4)
        vlds[r][lane] = vb[(size_t)st[r] * cH * cD + lane];
    int k = lane >> 1, hh = lane & 1;
    float4 kreg[8];
    {
        const float* kr = kb + (size_t)st[k] * cH * cE + hh * 32;
#pragma unroll
        for (int j = 0; j < 8; ++j) kreg[j] = ((const float4*)kr)[j];
    }
    __syncthreads();
    int cnt = counts[b];
    int off = moff[b];
    float scale = 1.0f - abk[b];
    float vbgd = vbg[(size_t)b * cD + lane];
    float stf = (lane < cK) ? (float)st[lane] : 0.f;
    const int* ml = mlist + (size_t)nh * cL + off;
    const size_t off1 = (size_t)cN * cL * cH * cD;
    const size_t off2 = off1 + (size_t)cN * cH * cL * cK;
    int slot = p * 4 + wid;             // 0..7
    for (int m0 = slot * 2; m0 < cnt; m0 += 8 * OSPLIT) {   // wave-uniform
        int m1 = m0 + 1;
        bool has1 = (m1 < cnt);                             // wave-uniform
        int l0 = ml[m0];
        int l1 = has1 ? ml[m1] : l0;
        const float* q0 = q + (((size_t)n * cL + l0) * cH + h) * cE + hh * 32;
        const float* q1 = q + (((size_t)n * cL + l1) * cH + h) * cE + hh * 32;
        float4 qa[8], qc[8];
#pragma unroll
        for (int j = 0; j < 8; ++j) {
            qa[j] = ((const float4*)q0)[j];
            qc[j] = ((const float4*)q1)[j];
        }
        // two independent half-dot chains (ascending e within half)
        float pa = 0.f, pc = 0.f;
#pragma unroll
        for (int j = 0; j < 8; ++j) {
            pa = fmaf(qa[j].x, kreg[j].x, pa); pc = fmaf(qc[j].x, kreg[j].x, pc);
            pa = fmaf(qa[j].y, kreg[j].y, pa); pc = fmaf(qc[j].y, kreg[j].y, pc);
            pa = fmaf(qa[j].z, kreg[j].z, pa); pc = fmaf(qc[j].z, kreg[j].z, pc);
            pa = fmaf(qa[j].w, kreg[j].w, pa); pc = fmaf(qc[j].w, kreg[j].w, pc);
        }
        float qk0 = pa + __shfl_xor(pa, 1);
        float qk1 = pc + __shfl_xor(pc, 1);
        float M0 = qk0, M1 = qk1;
#pragma unroll
        for (int o = 2; o < 64; o <<= 1) {
            M0 = fmaxf(M0, __shfl_xor(M0, o));
            M1 = fmaxf(M1, __shfl_xor(M1, o));
        }
        float ev0 = expf(0.125f * (qk0 - M0));
        float ev1 = expf(0.125f * (qk1 - M1));
        float d0 = ev0, d1 = ev1;
#pragma unroll
        for (int o = 2; o < 64; o <<= 1) {
            d0 += __shfl_xor(d0, o);
            d1 += __shfl_xor(d1, o);
        }
        float as0 = (ev0 / d0) * scale;
        float as1 = (ev1 / d1) * scale;
        if (!hh) { aslds[wid][0][k] = as0; aslds[wid][1][k] = as1; }
        float acc0 = 0.f, acc1 = 0.f;
#pragma unroll
        for (int j = 0; j < cK; ++j) {
            float vj = vlds[j][lane];
            acc0 = fmaf(aslds[wid][0][j], vj, acc0);
            acc1 = fmaf(aslds[wid][1][j], vj, acc1);
        }
        acc0 += vbgd; acc1 += vbgd;
        int qidx0 = nh * cL + l0;
        out[(((size_t)n * cL + l0) * cH + h) * cD + lane] = acc0;  // (N,L,H,D)
        if (lane < cK) {
            out[off1 + (size_t)qidx0 * cK + lane] = stf;           // sparse_index
            out[off2 + (size_t)qidx0 * cK + lane] = aslds[wid][0][lane];
        }
        if (has1) {
            int qidx1 = nh * cL + l1;
            out[(((size_t)n * cL + l1) * cH + h) * cD + lane] = acc1;
            if (lane < cK) {
                out[off1 + (size_t)qidx1 * cK + lane] = stf;
                out[off2 + (size_t)qidx1 * cK + lane] = aslds[wid][1][lane];
            }
        }
    }
}

// ---------------- launch -------------------------------------------------
extern "C" void kernel_launch(void* const* d_in, const int* in_sizes, int n_in,
                              void* d_out, int out_size, void* d_ws, size_t ws_size,
                              hipStream_t stream)
{
    (void)in_sizes; (void)n_in; (void)out_size; (void)ws_size;
    const float* q      = (const float*)d_in[0];
    const float* key    = (const float*)d_in[1];
    const float* val    = (const float*)d_in[2];
    const float* planes = (const float*)d_in[3];
    char* w = (char*)d_ws;
    unsigned int* bits = (unsigned int*)w;  w += (size_t)cN * cH * cL * 4;
    int*   cl     = (int*)w;                w += (size_t)cN * cH * cL * 4;
    int*   counts = (int*)w;                w += (size_t)cN * cH * cC * 4;
    float* abk    = (float*)w;              w += (size_t)cN * cH * cC * 4;
    float* Qg     = (float*)w;              w += (size_t)cN * cH * cC * cE * 4;
    float* vbg    = (float*)w;              w += (size_t)cN * cH * cC * cD * 4;
    int*   topkp  = (int*)w;                w += (size_t)cN * cH * cC * cK * 4;
    float* QK     = (float*)w;              w += (size_t)cNH * cC * cS * 4;      // 16 MB (QK -> P in place)
    float* part   = (float*)w;              w += (size_t)SK * cNH * cC * cD * 4; // 4 MB
    unsigned int* cent = (unsigned int*)w;  w += (size_t)cNH * cC * 4;           // 8 KB
    int*   partial = (int*)w;               w += (size_t)cNH * TILES * HW * 4;   // 2.2 MB
    int*   mlist  = (int*)w;                w += (size_t)cNH * cL * 4;           // 128 KB
    int*   moff   = (int*)w;                w += (size_t)cNH * cC * 4;           // 8 KB
    float* out = (float*)d_out;

    k_bits   <<<(cN * cH * cL) / 256, 256, 0, stream>>>(q, planes, bits);
    k_init   <<<(cNH * cC) / 256, 256, 0, stream>>>(bits, cent);
    for (int it = 0; it < cIT; ++it) {
        k_assign <<<cNH * TILES, 256, 0, stream>>>(bits, cent, partial, cl, 0);
        k_update <<<cNH, 256, 0, stream>>>(partial, cent, counts, moff, 0);
    }
    k_assign <<<cNH * TILES, 256, 0, stream>>>(bits, cent, partial, cl, 1);
    k_update <<<cNH, 256, 0, stream>>>(partial, cent, counts, moff, 1);
    k_rank   <<<cNH * TILES, 256, 0, stream>>>(cl, partial, moff, mlist);
    k_qg     <<<cNH * cC, 64, 0, stream>>>(q, mlist, moff, counts, Qg);
    k_qk_gemm<<<cNH * 16, 256, 0, stream>>>(key, Qg, QK);
    k_sel    <<<cNH * cC, 256, 0, stream>>>(QK, topkp, abk);
    k_pv     <<<cNH * SK * 2, 256, 0, stream>>>(QK, val, part);
    k_red    <<<(cNH * cC * cD) / 256, 256, 0, stream>>>(part, vbg);
    k_out    <<<cNH * cC * OSPLIT, 256, 0, stream>>>(q, key, val, mlist, moff,
                                                     counts, abk, vbg, topkp, out);
}